// Round 3
// baseline (461.341 us; speedup 1.0000x reference)
//
#include <hip/hip_runtime.h>
#include <math.h>

#define UT 1024
#define XS 52      // x-buffer row stride
#define ASTR 65    // A-buffer row stride (odd -> conflict-free column access)

__device__ __forceinline__ float wred16(float v) {
    v += __shfl_xor(v, 8); v += __shfl_xor(v, 4);
    v += __shfl_xor(v, 2); v += __shfl_xor(v, 1);
    return v;
}

// ---------------------------------------------------------------------------
// GCN on LDS buffers (verbatim from round 2, proven). x in/out stride XS,
// tmp scratch stride XS, A stride ASTR, Wl scratch for staged W (+bias row 50).
// ---------------------------------------------------------------------------
__device__ __forceinline__ void gcn_u(int n, int cin, int cout,
    float* __restrict__ x, float* __restrict__ tmp,
    const float* __restrict__ A, float* __restrict__ Wl,
    float* __restrict__ dis,
    const float* __restrict__ Wg, const float* __restrict__ bg, bool relu)
{
    const int tid = threadIdx.x;
    const int nso = (cout + 3) >> 2;
    for (int idx = tid; idx < 51 * 52; idx += UT) {
        int r = idx / 52, c = idx - r * 52;
        float v = 0.f;
        if (r < cin && c < cout) v = Wg[r * cout + c];
        else if (r == 50 && c < cout) v = bg[c];
        Wl[idx] = v;
    }
    {
        int r = tid >> 4, l = tid & 15;
        float s = 0.f;
        if (r < n) for (int j = l; j < n; j += 16) s += A[r * ASTR + j];
        s = wred16(s);
        if (l == 0 && r < n) dis[r] = 1.0f / sqrtf(2.0f + s);
    }
    __syncthreads();
    int nr2 = n >> 1;
    for (int it = tid; it < nr2 * nso; it += UT) {
        int i0 = (it / nso) * 2, o0 = (it - (it / nso) * nso) * 4;
        float a0=0,a1=0,a2=0,a3=0, b0=0,b1=0,b2=0,b3=0;
        for (int k = 0; k < cin; k++) {
            float4 w = *(const float4*)&Wl[k * 52 + o0];
            float x0 = x[i0 * XS + k], x1 = x[(i0 + 1) * XS + k];
            a0 = fmaf(x0, w.x, a0); a1 = fmaf(x0, w.y, a1);
            a2 = fmaf(x0, w.z, a2); a3 = fmaf(x0, w.w, a3);
            b0 = fmaf(x1, w.x, b0); b1 = fmaf(x1, w.y, b1);
            b2 = fmaf(x1, w.z, b2); b3 = fmaf(x1, w.w, b3);
        }
        float d0 = dis[i0], d1 = dis[i0 + 1];
        float4 t0; t0.x = a0*d0; t0.y = a1*d0; t0.z = a2*d0; t0.w = a3*d0;
        float4 t1; t1.x = b0*d1; t1.y = b1*d1; t1.z = b2*d1; t1.w = b3*d1;
        *(float4*)&tmp[i0 * XS + o0] = t0;
        *(float4*)&tmp[(i0 + 1) * XS + o0] = t1;
    }
    __syncthreads();
    for (int it = tid; it < nr2 * nso; it += UT) {
        int i0 = (it / nso) * 2, o0 = (it - (it / nso) * nso) * 4;
        float a0=0,a1=0,a2=0,a3=0, b0=0,b1=0,b2=0,b3=0;
        for (int j = 0; j < n; j++) {
            float4 t = *(const float4*)&tmp[j * XS + o0];
            float av0 = A[i0 * ASTR + j], av1 = A[(i0 + 1) * ASTR + j];
            a0 = fmaf(av0, t.x, a0); a1 = fmaf(av0, t.y, a1);
            a2 = fmaf(av0, t.z, a2); a3 = fmaf(av0, t.w, a3);
            b0 = fmaf(av1, t.x, b0); b1 = fmaf(av1, t.y, b1);
            b2 = fmaf(av1, t.z, b2); b3 = fmaf(av1, t.w, b3);
        }
        float4 bias = *(const float4*)&Wl[50 * 52 + o0];
        float4 s0 = *(const float4*)&tmp[i0 * XS + o0];
        float4 s1 = *(const float4*)&tmp[(i0 + 1) * XS + o0];
        float d0 = dis[i0], d1 = dis[i0 + 1];
        float4 r0, r1;
        r0.x = fmaf(d0, a0 + 2.f*s0.x, bias.x); r0.y = fmaf(d0, a1 + 2.f*s0.y, bias.y);
        r0.z = fmaf(d0, a2 + 2.f*s0.z, bias.z); r0.w = fmaf(d0, a3 + 2.f*s0.w, bias.w);
        r1.x = fmaf(d1, b0 + 2.f*s1.x, bias.x); r1.y = fmaf(d1, b1 + 2.f*s1.y, bias.y);
        r1.z = fmaf(d1, b2 + 2.f*s1.z, bias.z); r1.w = fmaf(d1, b3 + 2.f*s1.w, bias.w);
        if (relu) {
            r0.x = fmaxf(r0.x, 0.f); r0.y = fmaxf(r0.y, 0.f);
            r0.z = fmaxf(r0.z, 0.f); r0.w = fmaxf(r0.w, 0.f);
            r1.x = fmaxf(r1.x, 0.f); r1.y = fmaxf(r1.y, 0.f);
            r1.z = fmaxf(r1.z, 0.f); r1.w = fmaxf(r1.w, 0.f);
        }
        *(float4*)&x[i0 * XS + o0] = r0;
        *(float4*)&x[(i0 + 1) * XS + o0] = r1;
    }
    __syncthreads();
}

// ---------------------------------------------------------------------------
// NNConv phase: xl dense (64 x FIN) pre-filled, edges pre-loaded.
// out = relu(segmean_dst(msg) + x@rw + bias) -> xout stride XS.
// ---------------------------------------------------------------------------
template<int FIN>
__device__ __forceinline__ void nnconv_phase(
    const float* __restrict__ xl, float* __restrict__ sums,
    const int* __restrict__ srcl, const int* __restrict__ dstl,
    const float* __restrict__ eal, float* __restrict__ cnt,
    float* __restrict__ rwl,
    const float* __restrict__ mw, const float* __restrict__ mb,
    const float* __restrict__ rw, const float* __restrict__ bias,
    float* __restrict__ xout)
{
    const int tid = threadIdx.x;
    constexpr int ICN = FIN / 16;
    constexpr int ERN = UT / (32 * ICN);
    constexpr int EPT = 512 / ERN;
    for (int i = tid; i < 2048; i += UT) sums[i] = 0.f;
    for (int i = tid; i < FIN * 32; i += UT) rwl[i] = rw[i];
    if (tid < 64) cnt[tid] = 0.f;
    const int o = tid & 31, ic = (tid >> 5) & (ICN - 1), er = tid / (32 * ICN);
    float mwr[16], mbr[16];
    #pragma unroll
    for (int z = 0; z < 16; z++) {
        mwr[z] = mw[(ic * 16 + z) * 32 + o];
        mbr[z] = mb[(ic * 16 + z) * 32 + o];
    }
    __syncthreads();
    for (int e = tid; e < 512; e += UT) atomicAdd(&cnt[dstl[e]], 1.f);
    for (int e = er * EPT; e < er * EPT + EPT; e++) {
        int s = srcl[e]; int d = dstl[e]; float av = eal[e];
        float acc = 0.f;
        #pragma unroll
        for (int z = 0; z < 16; z += 4) {
            float4 xv = *(const float4*)&xl[s * FIN + ic * 16 + z];
            acc += xv.x * fmaxf(fmaf(av, mwr[z + 0], mbr[z + 0]), 0.f);
            acc += xv.y * fmaxf(fmaf(av, mwr[z + 1], mbr[z + 1]), 0.f);
            acc += xv.z * fmaxf(fmaf(av, mwr[z + 2], mbr[z + 2]), 0.f);
            acc += xv.w * fmaxf(fmaf(av, mwr[z + 3], mbr[z + 3]), 0.f);
        }
        acc += __shfl_down(acc, 32);         // combine ic pairs within wave
        if ((tid & 32) == 0) atomicAdd(&sums[d * 32 + o], acc);
    }
    __syncthreads();
    {   // epilogue: exactly 1024 items = (node, o-pair)
        int nn = tid >> 4, o0 = (tid & 15) * 2;
        float a0 = 0.f, a1 = 0.f;
        for (int i = 0; i < FIN; i++) {
            float xv = xl[nn * FIN + i];
            float2 w = *(const float2*)&rwl[i * 32 + o0];
            a0 = fmaf(xv, w.x, a0); a1 = fmaf(xv, w.y, a1);
        }
        float inv = 1.0f / fmaxf(cnt[nn], 1.f);
        float2 sv = *(const float2*)&sums[nn * 32 + o0];
        xout[nn * XS + o0]     = fmaxf(fmaf(sv.x, inv, a0 + bias[o0]),     0.f);
        xout[nn * XS + o0 + 1] = fmaxf(fmaf(sv.y, inv, a1 + bias[o0 + 1]), 0.f);
    }
    __syncthreads();
}

// ---------------------------------------------------------------------------
// UNet pieces (logic verbatim from round 2).
// ---------------------------------------------------------------------------
__device__ __forceinline__ void down_scores(int n, const float* __restrict__ wg,
                                            const float* __restrict__ px,
                                            float* __restrict__ scr)
{
    const int tid = threadIdx.x;
    int r = tid >> 4, l = tid & 15;
    float s = 0.f, wn = 0.f;
    for (int q = l; q < 50; q += 16) {
        float wv = wg[q];
        wn = fmaf(wv, wv, wn);
        s  = fmaf(px[r * XS + q], wv, s);
    }
    s = wred16(s); wn = wred16(wn);
    if (l == 0 && r < n) scr[r] = tanhf(s / sqrtf(wn));
}

__device__ __forceinline__ void down_rest(int n, int kk,
    float* __restrict__ px, float* __restrict__ pt_,
    float* __restrict__ pA, float* __restrict__ pF,
    float* __restrict__ scr, float* __restrict__ dis, float* __restrict__ svals,
    int* __restrict__ perm, const float* __restrict__ dw,
    const float* __restrict__ db)
{
    const int tid = threadIdx.x;
    __syncthreads();
    // bitonic top-k on wave 0 (desc score, asc index — lax.top_k semantics)
    if (tid < 64) {
        float v = (tid < n) ? scr[tid] : -2.0f;
        int id = tid;
        for (int sz = 2; sz <= 64; sz <<= 1)
            for (int st = sz >> 1; st > 0; st >>= 1) {
                float ov = __shfl_xor(v, st);
                int oi = __shfl_xor(id, st);
                bool up = ((tid & sz) == 0);
                bool lower = ((tid & st) == 0);
                bool less = (v > ov) || (v == ov && id < oi);
                bool keep = (up == lower) ? less : !less;
                if (!keep) { v = ov; id = oi; }
            }
        if (tid < kk) { perm[tid] = id; svals[tid] = v; }
    }
    __syncthreads();
    // Ag = Aold[:, perm] into pt_ (zero-padded cols); gather x->regs
    for (int idx = tid; idx < n * 13; idx += UT) {
        int m = idx / 13, u0 = (idx - (idx / 13) * 13) * 4;
        float4 gv;
        gv.x = (u0 + 0 < kk) ? pA[m * ASTR + perm[u0 + 0]] : 0.f;
        gv.y = (u0 + 1 < kk) ? pA[m * ASTR + perm[u0 + 1]] : 0.f;
        gv.z = (u0 + 2 < kk) ? pA[m * ASTR + perm[u0 + 2]] : 0.f;
        gv.w = (u0 + 3 < kk) ? pA[m * ASTR + perm[u0 + 3]] : 0.f;
        *(float4*)&pt_[m * XS + u0] = gv;
    }
    float gx0=0, gx1=0, gx2=0, gx3=0; int gdst = -1;
    if (tid < kk * 13) {
        int t = tid / 13, q0 = (tid - t * 13) * 4;
        float sv = svals[t]; int p = perm[t];
        gx0 = px[p * XS + q0 + 0] * sv; gx1 = px[p * XS + q0 + 1] * sv;
        gx2 = px[p * XS + q0 + 2] * sv; gx3 = px[p * XS + q0 + 3] * sv;
        gdst = t * XS + q0;
    }
    __syncthreads();
    if (gdst >= 0) {
        px[gdst] = gx0; px[gdst + 1] = gx1; px[gdst + 2] = gx2; px[gdst + 3] = gx3;
    }
    int nt2 = kk >> 1, nst = (kk + 3) >> 2;
    for (int it = tid; it < nt2 * nst; it += UT) {
        int t0 = (it / nst) * 2, u0 = (it - (it / nst) * nst) * 4;
        int p0 = perm[t0], p1 = perm[t0 + 1];
        float a0=0,a1=0,a2=0,a3=0, b0=0,b1=0,b2=0,b3=0;
        for (int m = 0; m < n; m++) {
            float4 gv = *(const float4*)&pt_[m * XS + u0];
            float q0v = pA[p0 * ASTR + m], q1v = pA[p1 * ASTR + m];
            a0 = fmaf(q0v, gv.x, a0); a1 = fmaf(q0v, gv.y, a1);
            a2 = fmaf(q0v, gv.z, a2); a3 = fmaf(q0v, gv.w, a3);
            b0 = fmaf(q1v, gv.x, b0); b1 = fmaf(q1v, gv.y, b1);
            b2 = fmaf(q1v, gv.z, b2); b3 = fmaf(q1v, gv.w, b3);
        }
        float4 g0 = *(const float4*)&pt_[p0 * XS + u0];
        float4 g1 = *(const float4*)&pt_[p1 * XS + u0];
        float v;
        v = a0 + 2.f*g0.x; pF[t0*ASTR + u0+0] = (u0+0 == t0) ? 0.f : v;
        v = a1 + 2.f*g0.y; pF[t0*ASTR + u0+1] = (u0+1 == t0) ? 0.f : v;
        v = a2 + 2.f*g0.z; pF[t0*ASTR + u0+2] = (u0+2 == t0) ? 0.f : v;
        v = a3 + 2.f*g0.w; pF[t0*ASTR + u0+3] = (u0+3 == t0) ? 0.f : v;
        v = b0 + 2.f*g1.x; pF[(t0+1)*ASTR + u0+0] = (u0+0 == t0+1) ? 0.f : v;
        v = b1 + 2.f*g1.y; pF[(t0+1)*ASTR + u0+1] = (u0+1 == t0+1) ? 0.f : v;
        v = b2 + 2.f*g1.z; pF[(t0+1)*ASTR + u0+2] = (u0+2 == t0+1) ? 0.f : v;
        v = b3 + 2.f*g1.w; pF[(t0+1)*ASTR + u0+3] = (u0+3 == t0+1) ? 0.f : v;
    }
    __syncthreads();
    gcn_u(kk, 50, 50, px, pt_, pF, pA, dis, dw, db, true);
}

// Full UNet: input x in xa (stride XS), output left in xb (or mean -> outp).
// Skip tensors live in per-thread scalar registers (fixed tid+k*1024 mapping).
__device__ __forceinline__ void unet_run(
    float* __restrict__ Aa, float* __restrict__ Ab,
    float* __restrict__ xa, float* __restrict__ xb,
    float* __restrict__ scr, float* __restrict__ dis, float* __restrict__ svals,
    int* __restrict__ permL, const float* __restrict__ wsAg,
    const float* __restrict__ dw0, const float* __restrict__ db0,
    const float* __restrict__ dws, const float* __restrict__ dbs,
    const float* __restrict__ pws, const float* __restrict__ uws,
    const float* __restrict__ ubs, const float* __restrict__ uwl,
    const float* __restrict__ ubl,
    float* __restrict__ outp, int g, int mean_mode)
{
    const int tid = threadIdx.x;
    for (int i = tid; i < 4160; i += UT) Aa[i] = wsAg[i];
    __syncthreads();
    float *pA = Aa, *pF = Ab, *px = xa, *pt_ = xb;

    gcn_u(64, 32, 50, px, pt_, pA, pF, dis, dw0, db0, true);

    // ---- down path (saves in scalar regs) ----
    down_scores(64, pws, px, scr);
    float xs0_0 = px[tid], xs0_1 = px[tid+1024], xs0_2 = px[tid+2048];
    float xs0_3 = (tid < 256) ? px[tid+3072] : 0.f;
    down_rest(64, 52, px, pt_, pA, pF, scr, dis, svals, permL, dws, dbs);
    { float* t = pA; pA = pF; pF = t; }

    down_scores(52, pws + 50, px, scr);
    float xs1_0 = px[tid], xs1_1 = px[tid+1024], xs1_2 = px[tid+2048];
    float xs1_3 = (tid < 256) ? px[tid+3072] : 0.f;
    float A1_0 = pA[tid], A1_1 = pA[tid+1024], A1_2 = pA[tid+2048];
    float A1_3 = (tid < 308) ? pA[tid+3072] : 0.f;           // 52*65=3380
    down_rest(52, 42, px, pt_, pA, pF, scr, dis, svals, permL + 64,
              dws + 2500, dbs + 50);
    { float* t = pA; pA = pF; pF = t; }

    down_scores(42, pws + 100, px, scr);
    float xs2_0 = px[tid], xs2_1 = px[tid+1024], xs2_2 = px[tid+2048];
    float xs2_3 = (tid < 256) ? px[tid+3072] : 0.f;
    float A2_0 = pA[tid], A2_1 = pA[tid+1024];
    float A2_2 = (tid < 682) ? pA[tid+2048] : 0.f;           // 42*65=2730
    down_rest(42, 34, px, pt_, pA, pF, scr, dis, svals, permL + 128,
              dws + 5000, dbs + 100);
    { float* t = pA; pA = pF; pF = t; }

    // ---- up path ----
    // i2=0, j=2: nj=42, kc=34
    pt_[tid] = xs2_0; pt_[tid+1024] = xs2_1; pt_[tid+2048] = xs2_2;
    if (tid < 256) pt_[tid+3072] = xs2_3;
    pF[tid] = A2_0; pF[tid+1024] = A2_1;
    if (tid < 682) pF[tid+2048] = A2_2;
    __syncthreads();
    for (int it = tid; it < 34 * 13; it += UT) {
        int t = it / 13, q0 = (it - t * 13) * 4;
        int p = permL[128 + t];
        pt_[p*XS+q0+0] += px[t*XS+q0+0]; pt_[p*XS+q0+1] += px[t*XS+q0+1];
        pt_[p*XS+q0+2] += px[t*XS+q0+2]; pt_[p*XS+q0+3] += px[t*XS+q0+3];
    }
    __syncthreads();
    gcn_u(42, 50, 50, pt_, px, pF, pA, dis, uws, ubs, true);
    { float* t = px; px = pt_; pt_ = t; t = pA; pA = pF; pF = t; }

    // i2=1, j=1: nj=52, kc=42
    pt_[tid] = xs1_0; pt_[tid+1024] = xs1_1; pt_[tid+2048] = xs1_2;
    if (tid < 256) pt_[tid+3072] = xs1_3;
    pF[tid] = A1_0; pF[tid+1024] = A1_1; pF[tid+2048] = A1_2;
    if (tid < 308) pF[tid+3072] = A1_3;
    __syncthreads();
    for (int it = tid; it < 42 * 13; it += UT) {
        int t = it / 13, q0 = (it - t * 13) * 4;
        int p = permL[64 + t];
        pt_[p*XS+q0+0] += px[t*XS+q0+0]; pt_[p*XS+q0+1] += px[t*XS+q0+1];
        pt_[p*XS+q0+2] += px[t*XS+q0+2]; pt_[p*XS+q0+3] += px[t*XS+q0+3];
    }
    __syncthreads();
    gcn_u(52, 50, 50, pt_, px, pF, pA, dis, uws + 2500, ubs + 50, true);
    { float* t = px; px = pt_; pt_ = t; t = pA; pA = pF; pF = t; }

    // i2=2, j=0: nj=64, kc=52, last gcn (no relu, cout=32)
    pt_[tid] = xs0_0; pt_[tid+1024] = xs0_1; pt_[tid+2048] = xs0_2;
    if (tid < 256) pt_[tid+3072] = xs0_3;
    for (int i = tid; i < 4160; i += UT) pF[i] = wsAg[i];
    __syncthreads();
    for (int it = tid; it < 52 * 13; it += UT) {
        int t = it / 13, q0 = (it - t * 13) * 4;
        int p = permL[t];
        pt_[p*XS+q0+0] += px[t*XS+q0+0]; pt_[p*XS+q0+1] += px[t*XS+q0+1];
        pt_[p*XS+q0+2] += px[t*XS+q0+2]; pt_[p*XS+q0+3] += px[t*XS+q0+3];
    }
    __syncthreads();
    gcn_u(64, 50, 32, pt_, px, pF, pA, dis, uwl, ubl, false);
    // final result now in pt_ == xb (3 swaps from xa)

    if (mean_mode) {
        int r = tid >> 4, l = tid & 15;
        if (r < 32) {
            float s = 0.f;
            for (int i = l; i < 64; i += 16) s += fmaxf(xb[i * XS + r], 0.f);
            s = wred16(s);
            if (l == 0) outp[(size_t)g * 32 + r] = s * (1.0f / 64.0f);
        }
        __syncthreads();
    }
}

// ---------------------------------------------------------------------------
// Fused megakernel: one block per graph, whole per-graph pipeline.
// ---------------------------------------------------------------------------
__global__ __launch_bounds__(UT)
void fused_kernel(
    const float* __restrict__ x1, const float* __restrict__ x2,
    const int* __restrict__ ei1, const int* __restrict__ ei2,
    const float* __restrict__ ea1, const float* __restrict__ ea2,
    const float* __restrict__ m1w, const float* __restrict__ m1b,
    const float* __restrict__ r1w, const float* __restrict__ c1b,
    const float* __restrict__ m2w, const float* __restrict__ m2b,
    const float* __restrict__ r2w, const float* __restrict__ c2b,
    const float* __restrict__ u1_0, const float* __restrict__ u1_1,
    const float* __restrict__ u1_2, const float* __restrict__ u1_3,
    const float* __restrict__ u1_4, const float* __restrict__ u1_5,
    const float* __restrict__ u1_6, const float* __restrict__ u1_7,
    const float* __restrict__ u1_8,
    const float* __restrict__ u2_0, const float* __restrict__ u2_1,
    const float* __restrict__ u2_2, const float* __restrict__ u2_3,
    const float* __restrict__ u2_4, const float* __restrict__ u2_5,
    const float* __restrict__ u2_6, const float* __restrict__ u2_7,
    const float* __restrict__ u2_8,
    float* __restrict__ wsA, float* __restrict__ rr)
{
    const int g = blockIdx.x, tid = threadIdx.x;
    __shared__ __align__(16) float smem[15424];   // 61.7 KB
    float* Aa    = smem;                 // 4160
    float* Ab    = smem + 4160;          // 4160
    float* xa    = smem + 8320;          // 3328
    float* xb    = smem + 11648;         // 3328
    float* scr   = smem + 14976;         // 64
    float* dis   = smem + 15040;         // 64
    float* svals = smem + 15104;         // 64
    int*   permL = (int*)(smem + 15168); // 192
    float* cnt   = smem + 15360;         // 64
    // nnconv aliases (A buffers dead during nnconv phases)
    float* xl   = Aa;                    // 4096 <= 4160
    float* sums = Ab;                    // 2048
    int*   srcl = (int*)(Ab + 2048);
    int*   dstl = (int*)(Ab + 2560);
    float* eal  = Ab + 3072;             // ends at 3584 <= 4160

    float* wsAg = wsA + (size_t)g * 4160;
    const int* eig; const float* eag; const float* xg;
    if (g < 128) {
        eig = ei1 + (size_t)g * 1024; eag = ea1 + (size_t)g * 512;
        xg = x1 + (size_t)g * 4096;
    } else {
        int h = g - 128;
        eig = ei2 + (size_t)h * 1024; eag = ea2 + (size_t)h * 512;
        xg = x2 + (size_t)h * 4096;
    }

    // ---- Phase 0: edges + adjacency (stride-65 image), persist to ws ----
    for (int e = tid; e < 512; e += UT) {
        srcl[e] = eig[e]; dstl[e] = eig[512 + e]; eal[e] = eag[e];
    }
    for (int i = tid; i < 4160; i += UT) Aa[i] = 0.f;
    __syncthreads();
    for (int e = tid; e < 512; e += UT) Aa[dstl[e] * ASTR + srcl[e]] = 1.f;
    __syncthreads();
    if (tid < 64) Aa[tid * ASTR + tid] = 0.f;
    __syncthreads();
    for (int i = tid; i < 4160; i += UT) wsAg[i] = Aa[i];
    __threadfence_block();
    __syncthreads();

    // ---- Phase 1: nnconv1 (FIN=64): xl from global, rw staged in xb ----
    for (int i = tid; i < 4096; i += UT) xl[i] = xg[i];
    __syncthreads();
    nnconv_phase<64>(xl, sums, srcl, dstl, eal, cnt, xb, m1w, m1b, r1w, c1b, xa);

    // ---- Phase 2: unet1 (result left in xb) ----
    unet_run(Aa, Ab, xa, xb, scr, dis, svals, permL, wsAg,
             u1_0, u1_1, u1_2, u1_3, u1_4, u1_5, u1_6, u1_7, u1_8,
             nullptr, g, 0);

    // ---- Phase 3: nnconv2 input prep + run (FIN=32) ----
    for (int idx = tid; idx < 2048; idx += UT) {
        int i = idx >> 5, o = idx & 31;
        xl[idx] = fmaxf(xb[i * XS + o], 0.f);     // relu(unet1 out) -> dense
    }
    for (int e = tid; e < 512; e += UT) {
        srcl[e] = eig[e]; dstl[e] = eig[512 + e]; eal[e] = eag[e];
    }
    __syncthreads();
    nnconv_phase<32>(xl, sums, srcl, dstl, eal, cnt, xb, m2w, m2b, r2w, c2b, xa);

    // ---- Phase 4: unet2 with mean epilogue -> rr ----
    unet_run(Aa, Ab, xa, xb, scr, dis, svals, permL, wsAg,
             u2_0, u2_1, u2_2, u2_3, u2_4, u2_5, u2_6, u2_7, u2_8,
             rr, g, 1);
}

// ---------------------------------------------------------------------------
// Head: out[b,h] = relu([r1,jw1,r2,jw2] @ bb_w + bb_b)
// ---------------------------------------------------------------------------
__global__ __launch_bounds__(256)
void head_kernel(const float* __restrict__ r,
                 const float* __restrict__ jw1, const float* __restrict__ jw2,
                 const float* __restrict__ bw, const float* __restrict__ bb,
                 float* __restrict__ out)
{
    const int b = blockIdx.x, h = threadIdx.x;
    float acc = bb[h];
    const float* r1 = r + (size_t)b * 32;
    const float* r2 = r + (size_t)(128 + b) * 32;
    #pragma unroll
    for (int q = 0; q < 32; q++) acc += r1[q] * bw[q * 256 + h];
    #pragma unroll
    for (int q = 0; q < 16; q++) acc += jw1[b * 16 + q] * bw[(32 + q) * 256 + h];
    #pragma unroll
    for (int q = 0; q < 32; q++) acc += r2[q] * bw[(48 + q) * 256 + h];
    #pragma unroll
    for (int q = 0; q < 16; q++) acc += jw2[b * 16 + q] * bw[(80 + q) * 256 + h];
    out[(size_t)b * 256 + h] = fmaxf(acc, 0.f);
}

// ---------------------------------------------------------------------------
extern "C" void kernel_launch(void* const* d_in, const int* in_sizes, int n_in,
                              void* d_out, int out_size, void* d_ws, size_t ws_size,
                              hipStream_t stream)
{
    const float* x1  = (const float*)d_in[0];
    const int*   ei1 = (const int*)  d_in[1];
    const float* ea1 = (const float*)d_in[2];
    const float* jw1 = (const float*)d_in[3];
    const float* x2  = (const float*)d_in[4];
    const int*   ei2 = (const int*)  d_in[5];
    const float* ea2 = (const float*)d_in[6];
    const float* jw2 = (const float*)d_in[7];
    const float* m1w = (const float*)d_in[8];
    const float* m1b = (const float*)d_in[9];
    const float* r1w = (const float*)d_in[10];
    const float* c1b = (const float*)d_in[11];
    const float* m2w = (const float*)d_in[12];
    const float* m2b = (const float*)d_in[13];
    const float* r2w = (const float*)d_in[14];
    const float* c2b = (const float*)d_in[15];
    const float* u1p[9]; for (int i = 0; i < 9; i++) u1p[i] = (const float*)d_in[16 + i];
    const float* u2p[9]; for (int i = 0; i < 9; i++) u2p[i] = (const float*)d_in[25 + i];
    const float* bbw = (const float*)d_in[34];
    const float* bbb = (const float*)d_in[35];

    char* ws = (char*)d_ws;
    float* wsA = (float*)ws;                             // 256*4160 floats
    float* rr  = (float*)(ws + 256ull * 4160 * 4);       // 256*32 floats
    (void)ws_size; (void)in_sizes; (void)n_in; (void)out_size;

    fused_kernel<<<256, UT, 0, stream>>>(
        x1, x2, ei1, ei2, ea1, ea2,
        m1w, m1b, r1w, c1b, m2w, m2b, r2w, c2b,
        u1p[0], u1p[1], u1p[2], u1p[3], u1p[4], u1p[5], u1p[6], u1p[7], u1p[8],
        u2p[0], u2p[1], u2p[2], u2p[3], u2p[4], u2p[5], u2p[6], u2p[7], u2p[8],
        wsA, rr);
    head_kernel<<<128, 256, 0, stream>>>(rr, jw1, jw2, bbw, bbb, (float*)d_out);
}

// Round 4
// 356.611 us; speedup vs baseline: 1.2937x; 1.2937x over previous
//
#include <hip/hip_runtime.h>
#include <math.h>

#define UT 1024
#define XS 52      // x-buffer row stride
#define ASTR 65    // A-buffer row stride (odd -> conflict-free column access)

__device__ __forceinline__ float wred16(float v) {
    v += __shfl_xor(v, 8); v += __shfl_xor(v, 4);
    v += __shfl_xor(v, 2); v += __shfl_xor(v, 1);
    return v;
}

// ---------------------------------------------------------------------------
// GCN on LDS buffers. 1-row x 4-col work items (n*13 <= 832 -> single pass,
// all waves fuller). Even/odd k and j accumulator pairs to halve chain depth.
// x in/out stride XS (in-place), tmp stride XS, A stride ASTR, Wl scratch.
// ---------------------------------------------------------------------------
__device__ __forceinline__ void gcn_u(int n, int cin, int cout,
    float* __restrict__ x, float* __restrict__ tmp,
    const float* __restrict__ A, float* __restrict__ Wl,
    float* __restrict__ dis,
    const float* __restrict__ Wg, const float* __restrict__ bg, bool relu)
{
    const int tid = threadIdx.x;
    const int nso = (cout + 3) >> 2;
    // stage W (+bias row 50)
    for (int idx = tid; idx < 51 * 52; idx += UT) {
        int r = idx / 52, c = idx - r * 52;
        float v = 0.f;
        if (r < cin && c < cout) v = Wg[r * cout + c];
        else if (r == 50 && c < cout) v = bg[c];
        Wl[idx] = v;
    }
    {   // dis[i] = 1/sqrt(2 + rowsum(A))
        int r = tid >> 4, l = tid & 15;
        float s = 0.f;
        if (r < n) for (int j = l; j < n; j += 16) s += A[r * ASTR + j];
        s = wred16(s);
        if (l == 0 && r < n) dis[r] = 1.0f / sqrtf(2.0f + s);
    }
    __syncthreads();
    const int items = n * nso;
    // stage 1: tmp[i,o0..3] = dis[i] * (x@W)[i,o0..3]   (cin is even)
    for (int it = tid; it < items; it += UT) {
        int i = it / nso, o0 = (it - i * nso) * 4;
        float a0=0,a1=0,a2=0,a3=0, b0=0,b1=0,b2=0,b3=0;
        for (int k = 0; k < cin; k += 2) {
            float4 w0 = *(const float4*)&Wl[k * 52 + o0];
            float4 w1 = *(const float4*)&Wl[(k + 1) * 52 + o0];
            float x0 = x[i * XS + k], x1 = x[i * XS + k + 1];
            a0 = fmaf(x0, w0.x, a0); a1 = fmaf(x0, w0.y, a1);
            a2 = fmaf(x0, w0.z, a2); a3 = fmaf(x0, w0.w, a3);
            b0 = fmaf(x1, w1.x, b0); b1 = fmaf(x1, w1.y, b1);
            b2 = fmaf(x1, w1.z, b2); b3 = fmaf(x1, w1.w, b3);
        }
        float d = dis[i];
        float4 t;
        t.x = (a0 + b0) * d; t.y = (a1 + b1) * d;
        t.z = (a2 + b2) * d; t.w = (a3 + b3) * d;
        *(float4*)&tmp[i * XS + o0] = t;
    }
    __syncthreads();
    // stage 2: x[i,o] = dis[i]*(A[i,:]@tmp[:,o] + 2*tmp[i,o]) + b[o]  (n even)
    for (int it = tid; it < items; it += UT) {
        int i = it / nso, o0 = (it - i * nso) * 4;
        float a0=0,a1=0,a2=0,a3=0, b0=0,b1=0,b2=0,b3=0;
        for (int j = 0; j < n; j += 2) {
            float4 t0 = *(const float4*)&tmp[j * XS + o0];
            float4 t1 = *(const float4*)&tmp[(j + 1) * XS + o0];
            float av0 = A[i * ASTR + j], av1 = A[i * ASTR + j + 1];
            a0 = fmaf(av0, t0.x, a0); a1 = fmaf(av0, t0.y, a1);
            a2 = fmaf(av0, t0.z, a2); a3 = fmaf(av0, t0.w, a3);
            b0 = fmaf(av1, t1.x, b0); b1 = fmaf(av1, t1.y, b1);
            b2 = fmaf(av1, t1.z, b2); b3 = fmaf(av1, t1.w, b3);
        }
        float4 bias = *(const float4*)&Wl[50 * 52 + o0];
        float4 s0 = *(const float4*)&tmp[i * XS + o0];
        float d = dis[i];
        float4 r;
        r.x = fmaf(d, (a0 + b0) + 2.f * s0.x, bias.x);
        r.y = fmaf(d, (a1 + b1) + 2.f * s0.y, bias.y);
        r.z = fmaf(d, (a2 + b2) + 2.f * s0.z, bias.z);
        r.w = fmaf(d, (a3 + b3) + 2.f * s0.w, bias.w);
        if (relu) {
            r.x = fmaxf(r.x, 0.f); r.y = fmaxf(r.y, 0.f);
            r.z = fmaxf(r.z, 0.f); r.w = fmaxf(r.w, 0.f);
        }
        *(float4*)&x[i * XS + o0] = r;
    }
    __syncthreads();
}

// ---------------------------------------------------------------------------
__device__ __forceinline__ void down_scores(int n, const float* __restrict__ wg,
                                            const float* __restrict__ px,
                                            float* __restrict__ scr)
{
    const int tid = threadIdx.x;
    int r = tid >> 4, l = tid & 15;
    float s = 0.f, wn = 0.f;
    for (int q = l; q < 50; q += 16) {
        float wv = wg[q];
        wn = fmaf(wv, wv, wn);
        s  = fmaf(px[r * XS + q], wv, s);
    }
    s = wred16(s); wn = wred16(wn);
    if (l == 0 && r < n) scr[r] = tanhf(s / sqrtf(wn));
}

__device__ __forceinline__ void down_rest(int n, int kk,
    float* __restrict__ px, float* __restrict__ pt_,
    float* __restrict__ pA, float* __restrict__ pF,
    float* __restrict__ scr, float* __restrict__ dis, float* __restrict__ svals,
    int* __restrict__ perm, const float* __restrict__ dw,
    const float* __restrict__ db)
{
    const int tid = threadIdx.x;
    __syncthreads();
    // bitonic top-k on wave 0 (desc score, asc index — lax.top_k semantics)
    if (tid < 64) {
        float v = (tid < n) ? scr[tid] : -2.0f;
        int id = tid;
        for (int sz = 2; sz <= 64; sz <<= 1)
            for (int st = sz >> 1; st > 0; st >>= 1) {
                float ov = __shfl_xor(v, st);
                int oi = __shfl_xor(id, st);
                bool up = ((tid & sz) == 0);
                bool lower = ((tid & st) == 0);
                bool less = (v > ov) || (v == ov && id < oi);
                bool keep = (up == lower) ? less : !less;
                if (!keep) { v = ov; id = oi; }
            }
        if (tid < kk) { perm[tid] = id; svals[tid] = v; }
    }
    __syncthreads();
    // Ag = Aold[:, perm] into pt_ (zero-padded cols); gather x -> regs
    for (int idx = tid; idx < n * 13; idx += UT) {
        int m = idx / 13, u0 = (idx - (idx / 13) * 13) * 4;
        float4 gv;
        gv.x = (u0 + 0 < kk) ? pA[m * ASTR + perm[u0 + 0]] : 0.f;
        gv.y = (u0 + 1 < kk) ? pA[m * ASTR + perm[u0 + 1]] : 0.f;
        gv.z = (u0 + 2 < kk) ? pA[m * ASTR + perm[u0 + 2]] : 0.f;
        gv.w = (u0 + 3 < kk) ? pA[m * ASTR + perm[u0 + 3]] : 0.f;
        *(float4*)&pt_[m * XS + u0] = gv;
    }
    float gx0=0, gx1=0, gx2=0, gx3=0; int gdst = -1;
    if (tid < kk * 13) {
        int t = tid / 13, q0 = (tid - t * 13) * 4;
        float sv = svals[t]; int p = perm[t];
        gx0 = px[p * XS + q0 + 0] * sv; gx1 = px[p * XS + q0 + 1] * sv;
        gx2 = px[p * XS + q0 + 2] * sv; gx3 = px[p * XS + q0 + 3] * sv;
        gdst = t * XS + q0;
    }
    __syncthreads();
    if (gdst >= 0) {
        px[gdst] = gx0; px[gdst + 1] = gx1; px[gdst + 2] = gx2; px[gdst + 3] = gx3;
    }
    // Anew[t,u] = 2*Ag[pt,u] + sum_m Aold[pt,m]*Ag[m,u]  (1-row x 4-col items)
    int nst = (kk + 3) >> 2;
    for (int it = tid; it < kk * nst; it += UT) {
        int t = it / nst, u0 = (it - t * nst) * 4;
        int p = perm[t];
        float a0=0,a1=0,a2=0,a3=0, c0=0,c1=0,c2=0,c3=0;
        for (int m = 0; m < n; m += 2) {
            float4 g0 = *(const float4*)&pt_[m * XS + u0];
            float4 g1 = *(const float4*)&pt_[(m + 1) * XS + u0];
            float q0v = pA[p * ASTR + m], q1v = pA[p * ASTR + m + 1];
            a0 = fmaf(q0v, g0.x, a0); a1 = fmaf(q0v, g0.y, a1);
            a2 = fmaf(q0v, g0.z, a2); a3 = fmaf(q0v, g0.w, a3);
            c0 = fmaf(q1v, g1.x, c0); c1 = fmaf(q1v, g1.y, c1);
            c2 = fmaf(q1v, g1.z, c2); c3 = fmaf(q1v, g1.w, c3);
        }
        float4 gg = *(const float4*)&pt_[p * XS + u0];
        float v;
        v = (a0 + c0) + 2.f * gg.x; pF[t * ASTR + u0 + 0] = (u0 + 0 == t) ? 0.f : v;
        v = (a1 + c1) + 2.f * gg.y; pF[t * ASTR + u0 + 1] = (u0 + 1 == t) ? 0.f : v;
        v = (a2 + c2) + 2.f * gg.z; pF[t * ASTR + u0 + 2] = (u0 + 2 == t) ? 0.f : v;
        v = (a3 + c3) + 2.f * gg.w; pF[t * ASTR + u0 + 3] = (u0 + 3 == t) ? 0.f : v;
    }
    __syncthreads();
    gcn_u(kk, 50, 50, px, pt_, pF, pA, dis, dw, db, true);
}

// ---------------------------------------------------------------------------
// UNet kernel: one block per graph, ws-backed skips (round-2 structure).
// ---------------------------------------------------------------------------
__global__ __launch_bounds__(UT)
void unet_kernel(const float* __restrict__ xin, const float* __restrict__ wsA,
                 const float* __restrict__ dw0, const float* __restrict__ db0,
                 const float* __restrict__ dws, const float* __restrict__ dbs,
                 const float* __restrict__ pws,
                 const float* __restrict__ uws, const float* __restrict__ ubs,
                 const float* __restrict__ uwl, const float* __restrict__ ubl,
                 float* __restrict__ ws_xs, float* __restrict__ ws_As,
                 float* __restrict__ outp, int mean_mode)
{
    const int g = blockIdx.x, tid = threadIdx.x;
    __shared__ __align__(16) float Aa[64 * ASTR];
    __shared__ __align__(16) float Ab[64 * ASTR];
    __shared__ __align__(16) float x0c[64 * XS];
    __shared__ __align__(16) float x1c[64 * XS];
    __shared__ float scr[64];
    __shared__ float dis[64];
    __shared__ float svals[64];
    __shared__ int   permL[192];

    float *pA = Aa, *pF = Ab, *px = x0c, *pt_ = x1c;
    float* xs_g = ws_xs + (size_t)g * 9984;   // 3 x 3328
    float* as_g = ws_As + (size_t)g * 6144;   // A1(3380) + A2(2730)
    const float* wsAg = wsA + (size_t)g * 4160;
    const int nsz[4] = {64, 52, 42, 34};

    {   // initial loads: x dense 64x32 -> stride XS; A strided image direct
        const float* xg = xin + (size_t)g * 2048;
        for (int idx = tid; idx < 512; idx += UT) {
            int i = idx >> 3, o0 = (idx & 7) * 4;
            *(float4*)&px[i * XS + o0] = *(const float4*)&xg[i * 32 + o0];
        }
        for (int idx = tid; idx < 4160; idx += UT) pA[idx] = wsAg[idx];
    }
    __syncthreads();

    gcn_u(64, 32, 50, px, pt_, pA, pF, dis, dw0, db0, true);

    // ---- down path ----
    for (int lvl = 0; lvl < 3; lvl++) {
        int n = nsz[lvl], kk = nsz[lvl + 1];
        down_scores(n, pws + lvl * 50, px, scr);
        {   // skip saves
            float* xd = xs_g + lvl * 3328;
            for (int idx = tid; idx < 3328; idx += UT) xd[idx] = px[idx];
            if (lvl == 1) for (int idx = tid; idx < 3380; idx += UT) as_g[idx] = pA[idx];
            if (lvl == 2) for (int idx = tid; idx < 2730; idx += UT) as_g[3380 + idx] = pA[idx];
        }
        down_rest(n, kk, px, pt_, pA, pF, scr, dis, svals, permL + lvl * 64,
                  dws + lvl * 2500, dbs + lvl * 50);
        { float* t = pA; pA = pF; pF = t; }
    }

    // ---- up path ----
    for (int i2 = 0; i2 < 3; i2++) {
        int j = 2 - i2;
        int kc = nsz[j + 1];
        {   // residual into pt_, A into pF
            const float* resg = xs_g + j * 3328;
            for (int idx = tid; idx < 3328; idx += UT) pt_[idx] = resg[idx];
            if (j == 0) {
                for (int idx = tid; idx < 4160; idx += UT) pF[idx] = wsAg[idx];
            } else if (j == 1) {
                for (int idx = tid; idx < 3380; idx += UT) pF[idx] = as_g[idx];
            } else {
                for (int idx = tid; idx < 2730; idx += UT) pF[idx] = as_g[3380 + idx];
            }
        }
        __syncthreads();
        const int* perm = permL + j * 64;
        for (int it = tid; it < kc * 13; it += UT) {
            int t = it / 13, q0 = (it - t * 13) * 4;
            int p = perm[t];
            pt_[p*XS+q0+0] += px[t*XS+q0+0]; pt_[p*XS+q0+1] += px[t*XS+q0+1];
            pt_[p*XS+q0+2] += px[t*XS+q0+2]; pt_[p*XS+q0+3] += px[t*XS+q0+3];
        }
        __syncthreads();
        if (i2 < 2)
            gcn_u(nsz[j], 50, 50, pt_, px, pF, pA, dis, uws + i2 * 2500, ubs + i2 * 50, true);
        else
            gcn_u(64, 50, 32, pt_, px, pF, pA, dis, uwl, ubl, false);
        { float* t2 = px; px = pt_; pt_ = t2; }
        { float* t2 = pA; pA = pF; pF = t2; }
    }

    // epilogue
    if (mean_mode) {
        int r = tid >> 4, l = tid & 15;
        if (r < 32) {
            float s = 0.f;
            for (int i = l; i < 64; i += 16) s += fmaxf(px[i * XS + r], 0.f);
            s = wred16(s);
            if (l == 0) outp[(size_t)g * 32 + r] = s * (1.0f / 64.0f);
        }
    } else {
        float* og = outp + (size_t)g * 2048;
        for (int idx = tid; idx < 512; idx += UT) {
            int i = idx >> 3, o0 = (idx & 7) * 4;
            float4 vv = *(const float4*)&px[i * XS + o0];
            vv.x = fmaxf(vv.x, 0.f); vv.y = fmaxf(vv.y, 0.f);
            vv.z = fmaxf(vv.z, 0.f); vv.w = fmaxf(vv.w, 0.f);
            *(float4*)&og[i * 32 + o0] = vv;
        }
    }
}

// ---------------------------------------------------------------------------
// NNConv core (post-load): edge loop with 4 split accumulators + epilogue.
// ---------------------------------------------------------------------------
template<int FIN>
__device__ __forceinline__ void nnconv_core(
    const float* __restrict__ xl, float* __restrict__ rwl,
    float* __restrict__ sums,
    const int* __restrict__ srcl, const int* __restrict__ dstl,
    const float* __restrict__ eal, const float* __restrict__ cnt,
    const float* __restrict__ mw, const float* __restrict__ mb,
    const float* __restrict__ bias, float* __restrict__ xout_g)
{
    const int tid = threadIdx.x;
    constexpr int ICN = FIN / 16;
    constexpr int EPT = 512 / (UT / (32 * ICN));
    const int o = tid & 31, ic = (tid >> 5) & (ICN - 1), er = tid / (32 * ICN);
    float mwr[16], mbr[16];
    #pragma unroll
    for (int z = 0; z < 16; z++) {
        mwr[z] = mw[(ic * 16 + z) * 32 + o];
        mbr[z] = mb[(ic * 16 + z) * 32 + o];
    }
    for (int e = er * EPT; e < er * EPT + EPT; e++) {
        int s = srcl[e]; int d = dstl[e]; float av = eal[e];
        float ac0 = 0.f, ac1 = 0.f, ac2 = 0.f, ac3 = 0.f;
        #pragma unroll
        for (int zb = 0; zb < 16; zb += 4) {
            float4 xv = *(const float4*)&xl[s * FIN + ic * 16 + zb];
            ac0 = fmaf(xv.x, fmaxf(fmaf(av, mwr[zb + 0], mbr[zb + 0]), 0.f), ac0);
            ac1 = fmaf(xv.y, fmaxf(fmaf(av, mwr[zb + 1], mbr[zb + 1]), 0.f), ac1);
            ac2 = fmaf(xv.z, fmaxf(fmaf(av, mwr[zb + 2], mbr[zb + 2]), 0.f), ac2);
            ac3 = fmaf(xv.w, fmaxf(fmaf(av, mwr[zb + 3], mbr[zb + 3]), 0.f), ac3);
        }
        float acc = (ac0 + ac1) + (ac2 + ac3);
        acc += __shfl_down(acc, 32);        // combine adjacent ic chunks
        if ((tid & 32) == 0) atomicAdd(&sums[d * 32 + o], acc);
    }
    __syncthreads();
    {   // epilogue: 1024 items = (node, o-pair)
        int nn = tid >> 4, o0 = (tid & 15) * 2;
        float a0 = 0.f, a1 = 0.f, b0 = 0.f, b1 = 0.f;
        for (int i = 0; i < FIN; i += 2) {
            float xv0 = xl[nn * FIN + i], xv1 = xl[nn * FIN + i + 1];
            float2 w0 = *(const float2*)&rwl[i * 32 + o0];
            float2 w1 = *(const float2*)&rwl[(i + 1) * 32 + o0];
            a0 = fmaf(xv0, w0.x, a0); a1 = fmaf(xv0, w0.y, a1);
            b0 = fmaf(xv1, w1.x, b0); b1 = fmaf(xv1, w1.y, b1);
        }
        float inv = 1.0f / fmaxf(cnt[nn], 1.f);
        float2 sv = *(const float2*)&sums[nn * 32 + o0];
        xout_g[nn * 32 + o0]     = fmaxf(fmaf(sv.x, inv, (a0 + b0) + bias[o0]),     0.f);
        xout_g[nn * 32 + o0 + 1] = fmaxf(fmaf(sv.y, inv, (a1 + b1) + bias[o0 + 1]), 0.f);
    }
}

// NNConv1 (FIN=64) + adjacency build (persisted to wsA as stride-65 image).
__global__ __launch_bounds__(UT)
void nnconv1_kernel(const float* __restrict__ x1, const float* __restrict__ x2,
                    const int* __restrict__ ei1, const int* __restrict__ ei2,
                    const float* __restrict__ ea1, const float* __restrict__ ea2,
                    const float* __restrict__ mw, const float* __restrict__ mb,
                    const float* __restrict__ rw, const float* __restrict__ bias,
                    float* __restrict__ wsA, float* __restrict__ xout)
{
    const int g = blockIdx.x, tid = threadIdx.x;
    __shared__ __align__(16) float xl[4096];
    __shared__ __align__(16) float rwl[2048];
    __shared__ __align__(16) float sums[2048];
    __shared__ __align__(16) float Al[4160];
    __shared__ int   srcl[512];
    __shared__ int   dstl[512];
    __shared__ float eal[512];
    __shared__ float cnt[64];

    const float* xg; const int* eig; const float* eag;
    if (g < 128) {
        xg = x1 + (size_t)g * 4096; eig = ei1 + (size_t)g * 1024; eag = ea1 + (size_t)g * 512;
    } else {
        int h = g - 128;
        xg = x2 + (size_t)h * 4096; eig = ei2 + (size_t)h * 1024; eag = ea2 + (size_t)h * 512;
    }
    for (int i = tid; i < 4096; i += UT) xl[i] = xg[i];
    for (int i = tid; i < 2048; i += UT) { rwl[i] = rw[i]; sums[i] = 0.f; }
    for (int e = tid; e < 512; e += UT) {
        srcl[e] = eig[e]; dstl[e] = eig[512 + e]; eal[e] = eag[e];
    }
    for (int i = tid; i < 4160; i += UT) Al[i] = 0.f;
    if (tid < 64) cnt[tid] = 0.f;
    __syncthreads();
    for (int e = tid; e < 512; e += UT) Al[dstl[e] * ASTR + srcl[e]] = 1.f;
    __syncthreads();
    if (tid < 64) Al[tid * ASTR + tid] = 0.f;
    for (int e = tid; e < 512; e += UT) atomicAdd(&cnt[dstl[e]], 1.f);
    __syncthreads();
    for (int i = tid; i < 4160; i += UT) wsA[(size_t)g * 4160 + i] = Al[i];

    nnconv_core<64>(xl, rwl, sums, srcl, dstl, eal, cnt, mw, mb, bias,
                    xout + (size_t)g * 2048);
}

// NNConv2 (FIN=32): x from unet1 output (already relu'd, dense 64x32).
__global__ __launch_bounds__(UT)
void nnconv2_kernel(const float* __restrict__ xin,
                    const int* __restrict__ ei1, const int* __restrict__ ei2,
                    const float* __restrict__ ea1, const float* __restrict__ ea2,
                    const float* __restrict__ mw, const float* __restrict__ mb,
                    const float* __restrict__ rw, const float* __restrict__ bias,
                    float* __restrict__ xout)
{
    const int g = blockIdx.x, tid = threadIdx.x;
    __shared__ __align__(16) float xl[2048];
    __shared__ __align__(16) float rwl[1024];
    __shared__ __align__(16) float sums[2048];
    __shared__ int   srcl[512];
    __shared__ int   dstl[512];
    __shared__ float eal[512];
    __shared__ float cnt[64];

    const int* eig; const float* eag;
    if (g < 128) { eig = ei1 + (size_t)g * 1024; eag = ea1 + (size_t)g * 512; }
    else { int h = g - 128; eig = ei2 + (size_t)h * 1024; eag = ea2 + (size_t)h * 512; }

    const float* xg = xin + (size_t)g * 2048;
    for (int i = tid; i < 2048; i += UT) { xl[i] = xg[i]; sums[i] = 0.f; }
    for (int i = tid; i < 1024; i += UT) rwl[i] = rw[i];
    for (int e = tid; e < 512; e += UT) {
        srcl[e] = eig[e]; dstl[e] = eig[512 + e]; eal[e] = eag[e];
    }
    if (tid < 64) cnt[tid] = 0.f;
    __syncthreads();
    for (int e = tid; e < 512; e += UT) atomicAdd(&cnt[dstl[e]], 1.f);
    __syncthreads();

    nnconv_core<32>(xl, rwl, sums, srcl, dstl, eal, cnt, mw, mb, bias,
                    xout + (size_t)g * 2048);
}

// ---------------------------------------------------------------------------
// Head: out[b,h] = relu([r1,jw1,r2,jw2] @ bb_w + bb_b)
// ---------------------------------------------------------------------------
__global__ __launch_bounds__(256)
void head_kernel(const float* __restrict__ r,
                 const float* __restrict__ jw1, const float* __restrict__ jw2,
                 const float* __restrict__ bw, const float* __restrict__ bb,
                 float* __restrict__ out)
{
    const int b = blockIdx.x, h = threadIdx.x;
    float acc = bb[h];
    const float* r1 = r + (size_t)b * 32;
    const float* r2 = r + (size_t)(128 + b) * 32;
    #pragma unroll
    for (int q = 0; q < 32; q++) acc += r1[q] * bw[q * 256 + h];
    #pragma unroll
    for (int q = 0; q < 16; q++) acc += jw1[b * 16 + q] * bw[(32 + q) * 256 + h];
    #pragma unroll
    for (int q = 0; q < 32; q++) acc += r2[q] * bw[(48 + q) * 256 + h];
    #pragma unroll
    for (int q = 0; q < 16; q++) acc += jw2[b * 16 + q] * bw[(80 + q) * 256 + h];
    out[(size_t)b * 256 + h] = fmaxf(acc, 0.f);
}

// ---------------------------------------------------------------------------
extern "C" void kernel_launch(void* const* d_in, const int* in_sizes, int n_in,
                              void* d_out, int out_size, void* d_ws, size_t ws_size,
                              hipStream_t stream)
{
    const float* x1  = (const float*)d_in[0];
    const int*   ei1 = (const int*)  d_in[1];
    const float* ea1 = (const float*)d_in[2];
    const float* jw1 = (const float*)d_in[3];
    const float* x2  = (const float*)d_in[4];
    const int*   ei2 = (const int*)  d_in[5];
    const float* ea2 = (const float*)d_in[6];
    const float* jw2 = (const float*)d_in[7];
    const float* m1w = (const float*)d_in[8];
    const float* m1b = (const float*)d_in[9];
    const float* r1w = (const float*)d_in[10];
    const float* c1b = (const float*)d_in[11];
    const float* m2w = (const float*)d_in[12];
    const float* m2b = (const float*)d_in[13];
    const float* r2w = (const float*)d_in[14];
    const float* c2b = (const float*)d_in[15];
    const float* u1p[9]; for (int i = 0; i < 9; i++) u1p[i] = (const float*)d_in[16 + i];
    const float* u2p[9]; for (int i = 0; i < 9; i++) u2p[i] = (const float*)d_in[25 + i];
    const float* bbw = (const float*)d_in[34];
    const float* bbb = (const float*)d_in[35];

    char* ws = (char*)d_ws;
    size_t off = 0;
    float* wsA  = (float*)(ws + off); off += 256ull * 4160 * 4;
    float* xc1  = (float*)(ws + off); off += 256ull * 2048 * 4;
    float* xu1  = (float*)(ws + off); off += 256ull * 2048 * 4;
    float* xc2  = (float*)(ws + off); off += 256ull * 2048 * 4;
    float* rr   = (float*)(ws + off); off += 256ull * 32 * 4;
    float* wxs  = (float*)(ws + off); off += 256ull * 9984 * 4;
    float* wAs  = (float*)(ws + off); off += 256ull * 6144 * 4;
    (void)ws_size; (void)in_sizes; (void)n_in; (void)out_size;

    nnconv1_kernel<<<256, UT, 0, stream>>>(x1, x2, ei1, ei2, ea1, ea2,
                                           m1w, m1b, r1w, c1b, wsA, xc1);
    unet_kernel<<<256, UT, 0, stream>>>(xc1, wsA,
        u1p[0], u1p[1], u1p[2], u1p[3], u1p[4], u1p[5], u1p[6], u1p[7], u1p[8],
        wxs, wAs, xu1, 0);
    nnconv2_kernel<<<256, UT, 0, stream>>>(xu1, ei1, ei2, ea1, ea2,
                                           m2w, m2b, r2w, c2b, xc2);
    unet_kernel<<<256, UT, 0, stream>>>(xc2, wsA,
        u2p[0], u2p[1], u2p[2], u2p[3], u2p[4], u2p[5], u2p[6], u2p[7], u2p[8],
        wxs, wAs, rr, 1);
    head_kernel<<<128, 256, 0, stream>>>(rr, jw1, jw2, bbw, bbb, (float*)d_out);
}

// Round 5
// 337.156 us; speedup vs baseline: 1.3683x; 1.0577x over previous
//
#include <hip/hip_runtime.h>
#include <math.h>

#define UT 1024
#define XS 52      // x-buffer row stride
#define ASTR 65    // A-buffer row stride (odd -> conflict-free column access)

__device__ __forceinline__ float wred16(float v) {
    v += __shfl_xor(v, 8); v += __shfl_xor(v, 4);
    v += __shfl_xor(v, 2); v += __shfl_xor(v, 1);
    return v;
}

// ---------------------------------------------------------------------------
// Dense GCN on LDS buffers (round-4, proven). 3 internal barriers.
// ---------------------------------------------------------------------------
__device__ __forceinline__ void gcn_u(int n, int cin, int cout,
    float* __restrict__ x, float* __restrict__ tmp,
    const float* __restrict__ A, float* __restrict__ Wl,
    float* __restrict__ dis,
    const float* __restrict__ Wg, const float* __restrict__ bg, bool relu)
{
    const int tid = threadIdx.x;
    const int nso = (cout + 3) >> 2;
    for (int idx = tid; idx < 51 * 52; idx += UT) {
        int r = idx / 52, c = idx - r * 52;
        float v = 0.f;
        if (r < cin && c < cout) v = Wg[r * cout + c];
        else if (r == 50 && c < cout) v = bg[c];
        Wl[idx] = v;
    }
    {   // dis[i] = 1/sqrt(2 + rowsum(A))
        int r = tid >> 4, l = tid & 15;
        float s = 0.f;
        if (r < n) for (int j = l; j < n; j += 16) s += A[r * ASTR + j];
        s = wred16(s);
        if (l == 0 && r < n) dis[r] = 1.0f / sqrtf(2.0f + s);
    }
    __syncthreads();
    const int items = n * nso;
    for (int it = tid; it < items; it += UT) {
        int i = it / nso, o0 = (it - i * nso) * 4;
        float a0=0,a1=0,a2=0,a3=0, b0=0,b1=0,b2=0,b3=0;
        for (int k = 0; k < cin; k += 2) {
            float4 w0 = *(const float4*)&Wl[k * 52 + o0];
            float4 w1 = *(const float4*)&Wl[(k + 1) * 52 + o0];
            float x0 = x[i * XS + k], x1 = x[i * XS + k + 1];
            a0 = fmaf(x0, w0.x, a0); a1 = fmaf(x0, w0.y, a1);
            a2 = fmaf(x0, w0.z, a2); a3 = fmaf(x0, w0.w, a3);
            b0 = fmaf(x1, w1.x, b0); b1 = fmaf(x1, w1.y, b1);
            b2 = fmaf(x1, w1.z, b2); b3 = fmaf(x1, w1.w, b3);
        }
        float d = dis[i];
        float4 t;
        t.x = (a0 + b0) * d; t.y = (a1 + b1) * d;
        t.z = (a2 + b2) * d; t.w = (a3 + b3) * d;
        *(float4*)&tmp[i * XS + o0] = t;
    }
    __syncthreads();
    for (int it = tid; it < items; it += UT) {
        int i = it / nso, o0 = (it - i * nso) * 4;
        float a0=0,a1=0,a2=0,a3=0, b0=0,b1=0,b2=0,b3=0;
        for (int j = 0; j < n; j += 2) {
            float4 t0 = *(const float4*)&tmp[j * XS + o0];
            float4 t1 = *(const float4*)&tmp[(j + 1) * XS + o0];
            float av0 = A[i * ASTR + j], av1 = A[i * ASTR + j + 1];
            a0 = fmaf(av0, t0.x, a0); a1 = fmaf(av0, t0.y, a1);
            a2 = fmaf(av0, t0.z, a2); a3 = fmaf(av0, t0.w, a3);
            b0 = fmaf(av1, t1.x, b0); b1 = fmaf(av1, t1.y, b1);
            b2 = fmaf(av1, t1.z, b2); b3 = fmaf(av1, t1.w, b3);
        }
        float4 bias = *(const float4*)&Wl[50 * 52 + o0];
        float4 s0 = *(const float4*)&tmp[i * XS + o0];
        float d = dis[i];
        float4 r;
        r.x = fmaf(d, (a0 + b0) + 2.f * s0.x, bias.x);
        r.y = fmaf(d, (a1 + b1) + 2.f * s0.y, bias.y);
        r.z = fmaf(d, (a2 + b2) + 2.f * s0.z, bias.z);
        r.w = fmaf(d, (a3 + b3) + 2.f * s0.w, bias.w);
        if (relu) {
            r.x = fmaxf(r.x, 0.f); r.y = fmaxf(r.y, 0.f);
            r.z = fmaxf(r.z, 0.f); r.w = fmaxf(r.w, 0.f);
        }
        *(float4*)&x[i * XS + o0] = r;
    }
    __syncthreads();
}

// ---------------------------------------------------------------------------
// Sparse GCN for n=64 with the ORIGINAL binary adjacency (dedup CSR).
// Stage-2 sums tmp rows over in-neighbors (entries exactly 1.0 -> bit-equal
// to the dense loop, ~8x fewer LDS reads). dis from exact integer degrees.
// ---------------------------------------------------------------------------
__device__ __forceinline__ void gcn_sparse(int cin, int cout,
    float* __restrict__ x, float* __restrict__ tmp,
    const int* __restrict__ csrOff, const int* __restrict__ csrCol,
    float* __restrict__ dis0, float* __restrict__ Wl,
    const float* __restrict__ Wg, const float* __restrict__ bg, bool relu)
{
    const int tid = threadIdx.x;
    const int nso = (cout + 3) >> 2;
    for (int idx = tid; idx < 51 * 52; idx += UT) {
        int r = idx / 52, c = idx - r * 52;
        float v = 0.f;
        if (r < cin && c < cout) v = Wg[r * cout + c];
        else if (r == 50 && c < cout) v = bg[c];
        Wl[idx] = v;
    }
    if (tid < 64)
        dis0[tid] = 1.0f / sqrtf(2.0f + (float)(csrOff[tid + 1] - csrOff[tid]));
    __syncthreads();
    const int items = 64 * nso;          // <= 832
    if (tid < items) {
        int i = tid / nso, o0 = (tid - i * nso) * 4;
        float a0=0,a1=0,a2=0,a3=0, b0=0,b1=0,b2=0,b3=0;
        for (int k = 0; k < cin; k += 2) {
            float4 w0 = *(const float4*)&Wl[k * 52 + o0];
            float4 w1 = *(const float4*)&Wl[(k + 1) * 52 + o0];
            float x0 = x[i * XS + k], x1 = x[i * XS + k + 1];
            a0 = fmaf(x0, w0.x, a0); a1 = fmaf(x0, w0.y, a1);
            a2 = fmaf(x0, w0.z, a2); a3 = fmaf(x0, w0.w, a3);
            b0 = fmaf(x1, w1.x, b0); b1 = fmaf(x1, w1.y, b1);
            b2 = fmaf(x1, w1.z, b2); b3 = fmaf(x1, w1.w, b3);
        }
        float d = dis0[i];
        float4 t;
        t.x = (a0 + b0) * d; t.y = (a1 + b1) * d;
        t.z = (a2 + b2) * d; t.w = (a3 + b3) * d;
        *(float4*)&tmp[i * XS + o0] = t;
    }
    __syncthreads();
    if (tid < items) {
        int i = tid / nso, o0 = (tid - i * nso) * 4;
        int base = csrOff[i], end = csrOff[i + 1];
        float a0 = 0.f, a1 = 0.f, a2 = 0.f, a3 = 0.f;
        for (int p = base; p < end; p++) {
            int j = csrCol[p];
            float4 t = *(const float4*)&tmp[j * XS + o0];
            a0 += t.x; a1 += t.y; a2 += t.z; a3 += t.w;
        }
        float4 bias = *(const float4*)&Wl[50 * 52 + o0];
        float4 s0 = *(const float4*)&tmp[i * XS + o0];
        float d = dis0[i];
        float4 r;
        r.x = fmaf(d, a0 + 2.f * s0.x, bias.x);
        r.y = fmaf(d, a1 + 2.f * s0.y, bias.y);
        r.z = fmaf(d, a2 + 2.f * s0.z, bias.z);
        r.w = fmaf(d, a3 + 2.f * s0.w, bias.w);
        if (relu) {
            r.x = fmaxf(r.x, 0.f); r.y = fmaxf(r.y, 0.f);
            r.z = fmaxf(r.z, 0.f); r.w = fmaxf(r.w, 0.f);
        }
        *(float4*)&x[tid / nso * XS + o0] = r;
    }
    __syncthreads();
}

// ---------------------------------------------------------------------------
__device__ __forceinline__ void down_scores(int n, const float* __restrict__ wg,
                                            const float* __restrict__ px,
                                            float* __restrict__ scr)
{
    const int tid = threadIdx.x;
    int r = tid >> 4, l = tid & 15;
    float s = 0.f, wn = 0.f;
    for (int q = l; q < 50; q += 16) {
        float wv = wg[q];
        wn = fmaf(wv, wv, wn);
        s  = fmaf(px[r * XS + q], wv, s);
    }
    s = wred16(s); wn = wred16(wn);
    if (l == 0 && r < n) scr[r] = tanhf(s / sqrtf(wn));
}

__device__ __forceinline__ void down_rest(int n, int kk,
    float* __restrict__ px, float* __restrict__ pt_,
    float* __restrict__ pA, float* __restrict__ pF,
    float* __restrict__ scr, float* __restrict__ dis, float* __restrict__ svals,
    int* __restrict__ perm, const float* __restrict__ dw,
    const float* __restrict__ db)
{
    const int tid = threadIdx.x;
    __syncthreads();
    // bitonic top-k on wave 0 (desc score, asc index — lax.top_k semantics)
    if (tid < 64) {
        float v = (tid < n) ? scr[tid] : -2.0f;
        int id = tid;
        for (int sz = 2; sz <= 64; sz <<= 1)
            for (int st = sz >> 1; st > 0; st >>= 1) {
                float ov = __shfl_xor(v, st);
                int oi = __shfl_xor(id, st);
                bool up = ((tid & sz) == 0);
                bool lower = ((tid & st) == 0);
                bool less = (v > ov) || (v == ov && id < oi);
                bool keep = (up == lower) ? less : !less;
                if (!keep) { v = ov; id = oi; }
            }
        if (tid < kk) { perm[tid] = id; svals[tid] = v; }
    }
    __syncthreads();
    for (int idx = tid; idx < n * 13; idx += UT) {
        int m = idx / 13, u0 = (idx - (idx / 13) * 13) * 4;
        float4 gv;
        gv.x = (u0 + 0 < kk) ? pA[m * ASTR + perm[u0 + 0]] : 0.f;
        gv.y = (u0 + 1 < kk) ? pA[m * ASTR + perm[u0 + 1]] : 0.f;
        gv.z = (u0 + 2 < kk) ? pA[m * ASTR + perm[u0 + 2]] : 0.f;
        gv.w = (u0 + 3 < kk) ? pA[m * ASTR + perm[u0 + 3]] : 0.f;
        *(float4*)&pt_[m * XS + u0] = gv;
    }
    float gx0=0, gx1=0, gx2=0, gx3=0; int gdst = -1;
    if (tid < kk * 13) {
        int t = tid / 13, q0 = (tid - t * 13) * 4;
        float sv = svals[t]; int p = perm[t];
        gx0 = px[p * XS + q0 + 0] * sv; gx1 = px[p * XS + q0 + 1] * sv;
        gx2 = px[p * XS + q0 + 2] * sv; gx3 = px[p * XS + q0 + 3] * sv;
        gdst = t * XS + q0;
    }
    __syncthreads();
    if (gdst >= 0) {
        px[gdst] = gx0; px[gdst + 1] = gx1; px[gdst + 2] = gx2; px[gdst + 3] = gx3;
    }
    int nst = (kk + 3) >> 2;
    for (int it = tid; it < kk * nst; it += UT) {
        int t = it / nst, u0 = (it - t * nst) * 4;
        int p = perm[t];
        float a0=0,a1=0,a2=0,a3=0, c0=0,c1=0,c2=0,c3=0;
        for (int m = 0; m < n; m += 2) {
            float4 g0 = *(const float4*)&pt_[m * XS + u0];
            float4 g1 = *(const float4*)&pt_[(m + 1) * XS + u0];
            float q0v = pA[p * ASTR + m], q1v = pA[p * ASTR + m + 1];
            a0 = fmaf(q0v, g0.x, a0); a1 = fmaf(q0v, g0.y, a1);
            a2 = fmaf(q0v, g0.z, a2); a3 = fmaf(q0v, g0.w, a3);
            c0 = fmaf(q1v, g1.x, c0); c1 = fmaf(q1v, g1.y, c1);
            c2 = fmaf(q1v, g1.z, c2); c3 = fmaf(q1v, g1.w, c3);
        }
        float4 gg = *(const float4*)&pt_[p * XS + u0];
        float v;
        v = (a0 + c0) + 2.f * gg.x; pF[t * ASTR + u0 + 0] = (u0 + 0 == t) ? 0.f : v;
        v = (a1 + c1) + 2.f * gg.y; pF[t * ASTR + u0 + 1] = (u0 + 1 == t) ? 0.f : v;
        v = (a2 + c2) + 2.f * gg.z; pF[t * ASTR + u0 + 2] = (u0 + 2 == t) ? 0.f : v;
        v = (a3 + c3) + 2.f * gg.w; pF[t * ASTR + u0 + 3] = (u0 + 3 == t) ? 0.f : v;
    }
    __syncthreads();
    gcn_u(kk, 50, 50, px, pt_, pF, pA, dis, dw, db, true);
}

// ---------------------------------------------------------------------------
// UNet kernel: one block per graph. Sparse CSR path for the two A0 gcns.
// ---------------------------------------------------------------------------
__global__ __launch_bounds__(UT)
void unet_kernel(const float* __restrict__ xin, const float* __restrict__ wsA,
                 const int* __restrict__ wsCsrO, const int* __restrict__ wsCsrC,
                 const float* __restrict__ dw0, const float* __restrict__ db0,
                 const float* __restrict__ dws, const float* __restrict__ dbs,
                 const float* __restrict__ pws,
                 const float* __restrict__ uws, const float* __restrict__ ubs,
                 const float* __restrict__ uwl, const float* __restrict__ ubl,
                 float* __restrict__ ws_xs, float* __restrict__ ws_As,
                 float* __restrict__ outp, int mean_mode)
{
    const int g = blockIdx.x, tid = threadIdx.x;
    __shared__ __align__(16) float Aa[64 * ASTR];
    __shared__ __align__(16) float Ab[64 * ASTR];
    __shared__ __align__(16) float x0c[64 * XS];
    __shared__ __align__(16) float x1c[64 * XS];
    __shared__ float scr[64];
    __shared__ float dis[64];
    __shared__ float dis0[64];
    __shared__ float svals[64];
    __shared__ int   permL[192];
    __shared__ int   csrOffL[65];
    __shared__ int   csrColL[512];

    float *pA = Aa, *pF = Ab, *px = x0c, *pt_ = x1c;
    float* xs_g = ws_xs + (size_t)g * 9984;   // 3 x 3328
    float* as_g = ws_As + (size_t)g * 6144;   // A1(3380) + A2(2730)
    const float* wsAg = wsA + (size_t)g * 4160;
    const int nsz[4] = {64, 52, 42, 34};

    {   // initial loads
        const float* xg = xin + (size_t)g * 2048;
        for (int idx = tid; idx < 512; idx += UT) {
            int i = idx >> 3, o0 = (idx & 7) * 4;
            *(float4*)&px[i * XS + o0] = *(const float4*)&xg[i * 32 + o0];
        }
        for (int idx = tid; idx < 4160; idx += UT) pA[idx] = wsAg[idx];
        if (tid < 65) csrOffL[tid] = wsCsrO[(size_t)g * 66 + tid];
        if (tid >= 128 && tid < 640) csrColL[tid - 128] = wsCsrC[(size_t)g * 512 + tid - 128];
    }
    __syncthreads();

    gcn_sparse(32, 50, px, pt_, csrOffL, csrColL, dis0, pF, dw0, db0, true);

    // ---- down path ----
    for (int lvl = 0; lvl < 3; lvl++) {
        int n = nsz[lvl], kk = nsz[lvl + 1];
        down_scores(n, pws + lvl * 50, px, scr);
        {   // skip saves
            float* xd = xs_g + lvl * 3328;
            for (int idx = tid; idx < 3328; idx += UT) xd[idx] = px[idx];
            if (lvl == 1) for (int idx = tid; idx < 3380; idx += UT) as_g[idx] = pA[idx];
            if (lvl == 2) for (int idx = tid; idx < 2730; idx += UT) as_g[3380 + idx] = pA[idx];
        }
        down_rest(n, kk, px, pt_, pA, pF, scr, dis, svals, permL + lvl * 64,
                  dws + lvl * 2500, dbs + lvl * 50);
        { float* t = pA; pA = pF; pF = t; }
    }

    // ---- up path ----
    for (int i2 = 0; i2 < 3; i2++) {
        int j = 2 - i2;
        int kc = nsz[j + 1];
        {   // residual into pt_; A into pF for dense levels only
            const float* resg = xs_g + j * 3328;
            for (int idx = tid; idx < 3328; idx += UT) pt_[idx] = resg[idx];
            if (j == 1) {
                for (int idx = tid; idx < 3380; idx += UT) pF[idx] = as_g[idx];
            } else if (j == 2) {
                for (int idx = tid; idx < 2730; idx += UT) pF[idx] = as_g[3380 + idx];
            }
        }
        __syncthreads();
        const int* perm = permL + j * 64;
        for (int it = tid; it < kc * 13; it += UT) {
            int t = it / 13, q0 = (it - t * 13) * 4;
            int p = perm[t];
            pt_[p*XS+q0+0] += px[t*XS+q0+0]; pt_[p*XS+q0+1] += px[t*XS+q0+1];
            pt_[p*XS+q0+2] += px[t*XS+q0+2]; pt_[p*XS+q0+3] += px[t*XS+q0+3];
        }
        __syncthreads();
        if (i2 < 2)
            gcn_u(nsz[j], 50, 50, pt_, px, pF, pA, dis, uws + i2 * 2500, ubs + i2 * 50, true);
        else
            gcn_sparse(50, 32, pt_, px, csrOffL, csrColL, dis0, pF, uwl, ubl, false);
        { float* t2 = px; px = pt_; pt_ = t2; }
        { float* t2 = pA; pA = pF; pF = t2; }
    }

    // epilogue
    if (mean_mode) {
        int r = tid >> 4, l = tid & 15;
        if (r < 32) {
            float s = 0.f;
            for (int i = l; i < 64; i += 16) s += fmaxf(px[i * XS + r], 0.f);
            s = wred16(s);
            if (l == 0) outp[(size_t)g * 32 + r] = s * (1.0f / 64.0f);
        }
    } else {
        float* og = outp + (size_t)g * 2048;
        for (int idx = tid; idx < 512; idx += UT) {
            int i = idx >> 3, o0 = (idx & 7) * 4;
            float4 vv = *(const float4*)&px[i * XS + o0];
            vv.x = fmaxf(vv.x, 0.f); vv.y = fmaxf(vv.y, 0.f);
            vv.z = fmaxf(vv.z, 0.f); vv.w = fmaxf(vv.w, 0.f);
            *(float4*)&og[i * 32 + o0] = vv;
        }
    }
}

// ---------------------------------------------------------------------------
// NNConv core with src-sorted edges: x-chunk cached in regs per src run.
// ---------------------------------------------------------------------------
template<int FIN>
__device__ __forceinline__ void nnconv_core(
    const float* __restrict__ xl, const float* __restrict__ rwl,
    float* __restrict__ sums,
    const int* __restrict__ sSrcL, const int* __restrict__ sDstL,
    const float* __restrict__ sEaL, const float* __restrict__ cnt,
    const float* __restrict__ mw, const float* __restrict__ mb,
    const float* __restrict__ bias, float* __restrict__ xout_g)
{
    const int tid = threadIdx.x;
    constexpr int ICN = FIN / 16;
    constexpr int EPT = 512 / (UT / (32 * ICN));
    const int o = tid & 31, ic = (tid >> 5) & (ICN - 1), er = tid / (32 * ICN);
    float mwr[16], mbr[16];
    #pragma unroll
    for (int z = 0; z < 16; z++) {
        mwr[z] = mw[(ic * 16 + z) * 32 + o];
        mbr[z] = mb[(ic * 16 + z) * 32 + o];
    }
    float xc[16];
    int sprev = -1;
    for (int e = er * EPT; e < er * EPT + EPT; e++) {
        int s = sSrcL[e];                     // wave-uniform
        if (s != sprev) {                     // wave-uniform branch
            sprev = s;
            *(float4*)&xc[0]  = *(const float4*)&xl[s * FIN + ic * 16 + 0];
            *(float4*)&xc[4]  = *(const float4*)&xl[s * FIN + ic * 16 + 4];
            *(float4*)&xc[8]  = *(const float4*)&xl[s * FIN + ic * 16 + 8];
            *(float4*)&xc[12] = *(const float4*)&xl[s * FIN + ic * 16 + 12];
        }
        float av = sEaL[e]; int d = sDstL[e];
        float ac0 = 0.f, ac1 = 0.f, ac2 = 0.f, ac3 = 0.f;
        #pragma unroll
        for (int zb = 0; zb < 16; zb += 4) {
            ac0 = fmaf(xc[zb + 0], fmaxf(fmaf(av, mwr[zb + 0], mbr[zb + 0]), 0.f), ac0);
            ac1 = fmaf(xc[zb + 1], fmaxf(fmaf(av, mwr[zb + 1], mbr[zb + 1]), 0.f), ac1);
            ac2 = fmaf(xc[zb + 2], fmaxf(fmaf(av, mwr[zb + 2], mbr[zb + 2]), 0.f), ac2);
            ac3 = fmaf(xc[zb + 3], fmaxf(fmaf(av, mwr[zb + 3], mbr[zb + 3]), 0.f), ac3);
        }
        float acc = (ac0 + ac1) + (ac2 + ac3);
        acc += __shfl_down(acc, 32);          // combine adjacent ic chunks
        if ((tid & 32) == 0) atomicAdd(&sums[d * 32 + o], acc);
    }
    __syncthreads();
    {   // epilogue: 1024 items = (node, o-pair)
        int nn = tid >> 4, o0 = (tid & 15) * 2;
        float a0 = 0.f, a1 = 0.f, b0 = 0.f, b1 = 0.f;
        for (int i = 0; i < FIN; i += 2) {
            float xv0 = xl[nn * FIN + i], xv1 = xl[nn * FIN + i + 1];
            float2 w0 = *(const float2*)&rwl[i * 32 + o0];
            float2 w1 = *(const float2*)&rwl[(i + 1) * 32 + o0];
            a0 = fmaf(xv0, w0.x, a0); a1 = fmaf(xv0, w0.y, a1);
            b0 = fmaf(xv1, w1.x, b0); b1 = fmaf(xv1, w1.y, b1);
        }
        float inv = 1.0f / fmaxf(cnt[nn], 1.f);
        float2 sv = *(const float2*)&sums[nn * 32 + o0];
        xout_g[nn * 32 + o0]     = fmaxf(fmaf(sv.x, inv, (a0 + b0) + bias[o0]),     0.f);
        xout_g[nn * 32 + o0 + 1] = fmaxf(fmaf(sv.y, inv, (a1 + b1) + bias[o0 + 1]), 0.f);
    }
}

// ---------------------------------------------------------------------------
// NNConv1 (FIN=64): builds A image, dedup CSR, deterministic src-sorted edge
// list (all persisted to ws), then runs the conv.
// ---------------------------------------------------------------------------
__global__ __launch_bounds__(UT)
void nnconv1_kernel(const float* __restrict__ x1, const float* __restrict__ x2,
                    const int* __restrict__ ei1, const int* __restrict__ ei2,
                    const float* __restrict__ ea1, const float* __restrict__ ea2,
                    const float* __restrict__ mw, const float* __restrict__ mb,
                    const float* __restrict__ rw, const float* __restrict__ bias,
                    float* __restrict__ wsA, int* __restrict__ wsSrt,
                    int* __restrict__ wsCsrO, int* __restrict__ wsCsrC,
                    float* __restrict__ xout)
{
    const int g = blockIdx.x, tid = threadIdx.x;
    __shared__ __align__(16) float xl[4096];
    __shared__ __align__(16) float rwl[2048];
    __shared__ __align__(16) float sums[2048];   // also sort scratch (ints)
    __shared__ __align__(16) float Al[4160];
    __shared__ int   srcl[512];
    __shared__ int   dstl[512];
    __shared__ float eal[512];
    __shared__ int   sSrcL[512];
    __shared__ int   sDstL[512];
    __shared__ float sEaL[512];
    __shared__ float cnt[64];
    __shared__ int   sTot[64];
    __shared__ int   sOff[65];
    __shared__ int   rowc[64];
    __shared__ int   csrOffL[65];

    const float* xg; const int* eig; const float* eag;
    if (g < 128) {
        xg = x1 + (size_t)g * 4096; eig = ei1 + (size_t)g * 1024; eag = ea1 + (size_t)g * 512;
    } else {
        int h = g - 128;
        xg = x2 + (size_t)h * 4096; eig = ei2 + (size_t)h * 1024; eag = ea2 + (size_t)h * 512;
    }
    int* chunkCnt = (int*)sums;                  // 16 chunks x 64 srcs

    // step 1: raw loads + zeroing
    for (int i = tid; i < 4096; i += UT) xl[i] = xg[i];
    for (int e = tid; e < 512; e += UT) {
        srcl[e] = eig[e]; dstl[e] = eig[512 + e]; eal[e] = eag[e];
    }
    for (int i = tid; i < 4160; i += UT) Al[i] = 0.f;
    for (int i = tid; i < 1024; i += UT) chunkCnt[i] = 0;
    if (tid < 64) cnt[tid] = 0.f;
    __syncthreads();
    // step 2: A scatter + per-chunk src counts
    for (int e = tid; e < 512; e += UT) Al[dstl[e] * ASTR + srcl[e]] = 1.f;
    for (int e = tid; e < 512; e += UT) atomicAdd(&chunkCnt[(e >> 5) * 64 + srcl[e]], 1);
    __syncthreads();
    // step 3: diag zero; chunk-exclusive run per src
    if (tid < 64) {
        Al[tid * ASTR + tid] = 0.f;
        int run = 0;
        for (int c = 0; c < 16; c++) {
            int t = chunkCnt[c * 64 + tid];
            chunkCnt[c * 64 + tid] = run; run += t;
        }
        sTot[tid] = run;
    }
    __syncthreads();
    // step 4: src prefix (wave 0); row nonzero counts; dst counts; rwl; wsA
    if (tid < 64) {
        int v = sTot[tid]; int x = v;
        #pragma unroll
        for (int d = 1; d < 64; d <<= 1) {
            int y = __shfl_up(x, d);
            if (tid >= d) x += y;
        }
        sOff[tid] = x - v;
        if (tid == 63) sOff[64] = x;
    }
    if (tid >= 64 && tid < 128) {
        int i = tid - 64; int c = 0;
        for (int j = 0; j < 64; j++) c += (Al[i * ASTR + j] != 0.f) ? 1 : 0;
        rowc[i] = c;
    }
    for (int e = tid; e < 512; e += UT) atomicAdd(&cnt[dstl[e]], 1.f);
    for (int i = tid; i < 2048; i += UT) rwl[i] = rw[i];
    for (int i = tid; i < 4160; i += UT) wsA[(size_t)g * 4160 + i] = Al[i];
    __syncthreads();
    // step 5: csr prefix (wave 0); stable sorted scatter
    if (tid < 64) {
        int v = rowc[tid]; int x = v;
        #pragma unroll
        for (int d = 1; d < 64; d <<= 1) {
            int y = __shfl_up(x, d);
            if (tid >= d) x += y;
        }
        csrOffL[tid] = x - v;
        if (tid == 63) csrOffL[64] = x;
    }
    for (int e = tid; e < 512; e += UT) {
        int s = srcl[e]; int c = e >> 5; int lr = 0;
        for (int e2 = (c << 5); e2 < e; e2++) lr += (srcl[e2] == s) ? 1 : 0;
        int pos = sOff[s] + chunkCnt[c * 64 + s] + lr;
        sSrcL[pos] = s; sDstL[pos] = dstl[e]; sEaL[pos] = eal[e];
    }
    __syncthreads();
    // step 6: persist csr + sorted; re-zero sums
    if (tid < 64) {
        int p = csrOffL[tid];
        for (int j = 0; j < 64; j++)
            if (Al[tid * ASTR + j] != 0.f) wsCsrC[(size_t)g * 512 + (p++)] = j;
    }
    if (tid >= 64 && tid < 129) wsCsrO[(size_t)g * 66 + (tid - 64)] = csrOffL[tid - 64];
    for (int e = tid; e < 512; e += UT) {
        wsSrt[(size_t)g * 1536 + e] = sSrcL[e];
        wsSrt[(size_t)g * 1536 + 512 + e] = sDstL[e];
        ((float*)wsSrt)[(size_t)g * 1536 + 1024 + e] = sEaL[e];
    }
    for (int i = tid; i < 2048; i += UT) sums[i] = 0.f;
    __syncthreads();

    nnconv_core<64>(xl, rwl, sums, sSrcL, sDstL, sEaL, cnt, mw, mb, bias,
                    xout + (size_t)g * 2048);
}

// ---------------------------------------------------------------------------
// NNConv2 (FIN=32): loads pre-sorted edges from ws.
// ---------------------------------------------------------------------------
__global__ __launch_bounds__(UT)
void nnconv2_kernel(const float* __restrict__ xin,
                    const int* __restrict__ wsSrt,
                    const float* __restrict__ mw, const float* __restrict__ mb,
                    const float* __restrict__ rw, const float* __restrict__ bias,
                    float* __restrict__ xout)
{
    const int g = blockIdx.x, tid = threadIdx.x;
    __shared__ __align__(16) float xl[2048];
    __shared__ __align__(16) float rwl[1024];
    __shared__ __align__(16) float sums[2048];
    __shared__ int   sSrcL[512];
    __shared__ int   sDstL[512];
    __shared__ float sEaL[512];
    __shared__ float cnt[64];

    const float* xg = xin + (size_t)g * 2048;
    for (int i = tid; i < 2048; i += UT) { xl[i] = xg[i]; sums[i] = 0.f; }
    for (int i = tid; i < 1024; i += UT) rwl[i] = rw[i];
    for (int e = tid; e < 512; e += UT) {
        sSrcL[e] = wsSrt[(size_t)g * 1536 + e];
        sDstL[e] = wsSrt[(size_t)g * 1536 + 512 + e];
        sEaL[e]  = ((const float*)wsSrt)[(size_t)g * 1536 + 1024 + e];
    }
    if (tid < 64) cnt[tid] = 0.f;
    __syncthreads();
    for (int e = tid; e < 512; e += UT) atomicAdd(&cnt[sDstL[e]], 1.f);
    __syncthreads();

    nnconv_core<32>(xl, rwl, sums, sSrcL, sDstL, sEaL, cnt, mw, mb, bias,
                    xout + (size_t)g * 2048);
}

// ---------------------------------------------------------------------------
// Head: out[b,h] = relu([r1,jw1,r2,jw2] @ bb_w + bb_b)
// ---------------------------------------------------------------------------
__global__ __launch_bounds__(256)
void head_kernel(const float* __restrict__ r,
                 const float* __restrict__ jw1, const float* __restrict__ jw2,
                 const float* __restrict__ bw, const float* __restrict__ bb,
                 float* __restrict__ out)
{
    const int b = blockIdx.x, h = threadIdx.x;
    float acc = bb[h];
    const float* r1 = r + (size_t)b * 32;
    const float* r2 = r + (size_t)(128 + b) * 32;
    #pragma unroll
    for (int q = 0; q < 32; q++) acc += r1[q] * bw[q * 256 + h];
    #pragma unroll
    for (int q = 0; q < 16; q++) acc += jw1[b * 16 + q] * bw[(32 + q) * 256 + h];
    #pragma unroll
    for (int q = 0; q < 32; q++) acc += r2[q] * bw[(48 + q) * 256 + h];
    #pragma unroll
    for (int q = 0; q < 16; q++) acc += jw2[b * 16 + q] * bw[(80 + q) * 256 + h];
    out[(size_t)b * 256 + h] = fmaxf(acc, 0.f);
}

// ---------------------------------------------------------------------------
extern "C" void kernel_launch(void* const* d_in, const int* in_sizes, int n_in,
                              void* d_out, int out_size, void* d_ws, size_t ws_size,
                              hipStream_t stream)
{
    const float* x1  = (const float*)d_in[0];
    const int*   ei1 = (const int*)  d_in[1];
    const float* ea1 = (const float*)d_in[2];
    const float* jw1 = (const float*)d_in[3];
    const float* x2  = (const float*)d_in[4];
    const int*   ei2 = (const int*)  d_in[5];
    const float* ea2 = (const float*)d_in[6];
    const float* jw2 = (const float*)d_in[7];
    const float* m1w = (const float*)d_in[8];
    const float* m1b = (const float*)d_in[9];
    const float* r1w = (const float*)d_in[10];
    const float* c1b = (const float*)d_in[11];
    const float* m2w = (const float*)d_in[12];
    const float* m2b = (const float*)d_in[13];
    const float* r2w = (const float*)d_in[14];
    const float* c2b = (const float*)d_in[15];
    const float* u1p[9]; for (int i = 0; i < 9; i++) u1p[i] = (const float*)d_in[16 + i];
    const float* u2p[9]; for (int i = 0; i < 9; i++) u2p[i] = (const float*)d_in[25 + i];
    const float* bbw = (const float*)d_in[34];
    const float* bbb = (const float*)d_in[35];

    char* ws = (char*)d_ws;
    size_t off = 0;
    float* wsA  = (float*)(ws + off); off += 256ull * 4160 * 4;
    float* xc1  = (float*)(ws + off); off += 256ull * 2048 * 4;
    float* xu1  = (float*)(ws + off); off += 256ull * 2048 * 4;
    float* xc2  = (float*)(ws + off); off += 256ull * 2048 * 4;
    float* rr   = (float*)(ws + off); off += 256ull * 32 * 4;
    float* wxs  = (float*)(ws + off); off += 256ull * 9984 * 4;
    float* wAs  = (float*)(ws + off); off += 256ull * 6144 * 4;
    int*   wSrt = (int*)  (ws + off); off += 256ull * 1536 * 4;
    int*   wCsO = (int*)  (ws + off); off += 256ull * 66 * 4;
    int*   wCsC = (int*)  (ws + off); off += 256ull * 512 * 4;
    (void)ws_size; (void)in_sizes; (void)n_in; (void)out_size;

    nnconv1_kernel<<<256, UT, 0, stream>>>(x1, x2, ei1, ei2, ea1, ea2,
                                           m1w, m1b, r1w, c1b,
                                           wsA, wSrt, wCsO, wCsC, xc1);
    unet_kernel<<<256, UT, 0, stream>>>(xc1, wsA, wCsO, wCsC,
        u1p[0], u1p[1], u1p[2], u1p[3], u1p[4], u1p[5], u1p[6], u1p[7], u1p[8],
        wxs, wAs, xu1, 0);
    nnconv2_kernel<<<256, UT, 0, stream>>>(xu1, wSrt, m2w, m2b, r2w, c2b, xc2);
    unet_kernel<<<256, UT, 0, stream>>>(xc2, wsA, wCsO, wCsC,
        u2p[0], u2p[1], u2p[2], u2p[3], u2p[4], u2p[5], u2p[6], u2p[7], u2p[8],
        wxs, wAs, rr, 1);
    head_kernel<<<128, 256, 0, stream>>>(rr, jw1, jw2, bbw, bbb, (float*)d_out);
}

// Round 6
// 303.991 us; speedup vs baseline: 1.5176x; 1.1091x over previous
//
#include <hip/hip_runtime.h>
#include <math.h>

#define UT 1024
#define XS 52      // x-buffer row stride
#define ASTR 65    // A-buffer row stride (odd -> conflict-free column access)

__device__ __forceinline__ float wred16(float v) {
    v += __shfl_xor(v, 8); v += __shfl_xor(v, 4);
    v += __shfl_xor(v, 2); v += __shfl_xor(v, 1);
    return v;
}

// ---------------------------------------------------------------------------
// Dense GCN on LDS buffers (proven). 3 internal barriers.
// ---------------------------------------------------------------------------
__device__ __forceinline__ void gcn_u(int n, int cin, int cout,
    float* __restrict__ x, float* __restrict__ tmp,
    const float* __restrict__ A, float* __restrict__ Wl,
    float* __restrict__ dis,
    const float* __restrict__ Wg, const float* __restrict__ bg, bool relu)
{
    const int tid = threadIdx.x;
    const int nso = (cout + 3) >> 2;
    for (int idx = tid; idx < 51 * 52; idx += UT) {
        int r = idx / 52, c = idx - r * 52;
        float v = 0.f;
        if (r < cin && c < cout) v = Wg[r * cout + c];
        else if (r == 50 && c < cout) v = bg[c];
        Wl[idx] = v;
    }
    {   // dis[i] = 1/sqrt(2 + rowsum(A))
        int r = tid >> 4, l = tid & 15;
        float s = 0.f;
        if (r < n) for (int j = l; j < n; j += 16) s += A[r * ASTR + j];
        s = wred16(s);
        if (l == 0 && r < n) dis[r] = 1.0f / sqrtf(2.0f + s);
    }
    __syncthreads();
    const int items = n * nso;
    for (int it = tid; it < items; it += UT) {
        int i = it / nso, o0 = (it - i * nso) * 4;
        float a0=0,a1=0,a2=0,a3=0, b0=0,b1=0,b2=0,b3=0;
        for (int k = 0; k < cin; k += 2) {
            float4 w0 = *(const float4*)&Wl[k * 52 + o0];
            float4 w1 = *(const float4*)&Wl[(k + 1) * 52 + o0];
            float x0 = x[i * XS + k], x1 = x[i * XS + k + 1];
            a0 = fmaf(x0, w0.x, a0); a1 = fmaf(x0, w0.y, a1);
            a2 = fmaf(x0, w0.z, a2); a3 = fmaf(x0, w0.w, a3);
            b0 = fmaf(x1, w1.x, b0); b1 = fmaf(x1, w1.y, b1);
            b2 = fmaf(x1, w1.z, b2); b3 = fmaf(x1, w1.w, b3);
        }
        float d = dis[i];
        float4 t;
        t.x = (a0 + b0) * d; t.y = (a1 + b1) * d;
        t.z = (a2 + b2) * d; t.w = (a3 + b3) * d;
        *(float4*)&tmp[i * XS + o0] = t;
    }
    __syncthreads();
    for (int it = tid; it < items; it += UT) {
        int i = it / nso, o0 = (it - i * nso) * 4;
        float a0=0,a1=0,a2=0,a3=0, b0=0,b1=0,b2=0,b3=0;
        for (int j = 0; j < n; j += 2) {
            float4 t0 = *(const float4*)&tmp[j * XS + o0];
            float4 t1 = *(const float4*)&tmp[(j + 1) * XS + o0];
            float av0 = A[i * ASTR + j], av1 = A[i * ASTR + j + 1];
            a0 = fmaf(av0, t0.x, a0); a1 = fmaf(av0, t0.y, a1);
            a2 = fmaf(av0, t0.z, a2); a3 = fmaf(av0, t0.w, a3);
            b0 = fmaf(av1, t1.x, b0); b1 = fmaf(av1, t1.y, b1);
            b2 = fmaf(av1, t1.z, b2); b3 = fmaf(av1, t1.w, b3);
        }
        float4 bias = *(const float4*)&Wl[50 * 52 + o0];
        float4 s0 = *(const float4*)&tmp[i * XS + o0];
        float d = dis[i];
        float4 r;
        r.x = fmaf(d, (a0 + b0) + 2.f * s0.x, bias.x);
        r.y = fmaf(d, (a1 + b1) + 2.f * s0.y, bias.y);
        r.z = fmaf(d, (a2 + b2) + 2.f * s0.z, bias.z);
        r.w = fmaf(d, (a3 + b3) + 2.f * s0.w, bias.w);
        if (relu) {
            r.x = fmaxf(r.x, 0.f); r.y = fmaxf(r.y, 0.f);
            r.z = fmaxf(r.z, 0.f); r.w = fmaxf(r.w, 0.f);
        }
        *(float4*)&x[i * XS + o0] = r;
    }
    __syncthreads();
}

// ---------------------------------------------------------------------------
// Sparse GCN for n=64 with the ORIGINAL binary adjacency (dedup CSR).
// ---------------------------------------------------------------------------
__device__ __forceinline__ void gcn_sparse(int cin, int cout,
    float* __restrict__ x, float* __restrict__ tmp,
    const int* __restrict__ csrOff, const int* __restrict__ csrCol,
    float* __restrict__ dis0, float* __restrict__ Wl,
    const float* __restrict__ Wg, const float* __restrict__ bg, bool relu)
{
    const int tid = threadIdx.x;
    const int nso = (cout + 3) >> 2;
    for (int idx = tid; idx < 51 * 52; idx += UT) {
        int r = idx / 52, c = idx - r * 52;
        float v = 0.f;
        if (r < cin && c < cout) v = Wg[r * cout + c];
        else if (r == 50 && c < cout) v = bg[c];
        Wl[idx] = v;
    }
    if (tid < 64)
        dis0[tid] = 1.0f / sqrtf(2.0f + (float)(csrOff[tid + 1] - csrOff[tid]));
    __syncthreads();
    const int items = 64 * nso;          // <= 832
    if (tid < items) {
        int i = tid / nso, o0 = (tid - i * nso) * 4;
        float a0=0,a1=0,a2=0,a3=0, b0=0,b1=0,b2=0,b3=0;
        for (int k = 0; k < cin; k += 2) {
            float4 w0 = *(const float4*)&Wl[k * 52 + o0];
            float4 w1 = *(const float4*)&Wl[(k + 1) * 52 + o0];
            float x0 = x[i * XS + k], x1 = x[i * XS + k + 1];
            a0 = fmaf(x0, w0.x, a0); a1 = fmaf(x0, w0.y, a1);
            a2 = fmaf(x0, w0.z, a2); a3 = fmaf(x0, w0.w, a3);
            b0 = fmaf(x1, w1.x, b0); b1 = fmaf(x1, w1.y, b1);
            b2 = fmaf(x1, w1.z, b2); b3 = fmaf(x1, w1.w, b3);
        }
        float d = dis0[i];
        float4 t;
        t.x = (a0 + b0) * d; t.y = (a1 + b1) * d;
        t.z = (a2 + b2) * d; t.w = (a3 + b3) * d;
        *(float4*)&tmp[i * XS + o0] = t;
    }
    __syncthreads();
    if (tid < items) {
        int i = tid / nso, o0 = (tid - i * nso) * 4;
        int base = csrOff[i], end = csrOff[i + 1];
        float a0 = 0.f, a1 = 0.f, a2 = 0.f, a3 = 0.f;
        for (int p = base; p < end; p++) {
            int j = csrCol[p];
            float4 t = *(const float4*)&tmp[j * XS + o0];
            a0 += t.x; a1 += t.y; a2 += t.z; a3 += t.w;
        }
        float4 bias = *(const float4*)&Wl[50 * 52 + o0];
        float4 s0 = *(const float4*)&tmp[i * XS + o0];
        float d = dis0[i];
        float4 r;
        r.x = fmaf(d, a0 + 2.f * s0.x, bias.x);
        r.y = fmaf(d, a1 + 2.f * s0.y, bias.y);
        r.z = fmaf(d, a2 + 2.f * s0.z, bias.z);
        r.w = fmaf(d, a3 + 2.f * s0.w, bias.w);
        if (relu) {
            r.x = fmaxf(r.x, 0.f); r.y = fmaxf(r.y, 0.f);
            r.z = fmaxf(r.z, 0.f); r.w = fmaxf(r.w, 0.f);
        }
        *(float4*)&x[i * XS + o0] = r;
    }
    __syncthreads();
}

// ---------------------------------------------------------------------------
__device__ __forceinline__ void down_scores(int n, const float* __restrict__ wg,
                                            const float* __restrict__ px,
                                            float* __restrict__ scr)
{
    const int tid = threadIdx.x;
    int r = tid >> 4, l = tid & 15;
    float s = 0.f, wn = 0.f;
    for (int q = l; q < 50; q += 16) {
        float wv = wg[q];
        wn = fmaf(wv, wv, wn);
        s  = fmaf(px[r * XS + q], wv, s);
    }
    s = wred16(s); wn = wred16(wn);
    if (l == 0 && r < n) scr[r] = tanhf(s / sqrtf(wn));
}

__device__ __forceinline__ void down_rest(int n, int kk,
    float* __restrict__ px, float* __restrict__ pt_,
    float* __restrict__ pA, float* __restrict__ pF,
    float* __restrict__ scr, float* __restrict__ dis, float* __restrict__ svals,
    int* __restrict__ perm, const float* __restrict__ dw,
    const float* __restrict__ db)
{
    const int tid = threadIdx.x;
    __syncthreads();
    // bitonic top-k on wave 0 (desc score, asc index — lax.top_k semantics)
    if (tid < 64) {
        float v = (tid < n) ? scr[tid] : -2.0f;
        int id = tid;
        for (int sz = 2; sz <= 64; sz <<= 1)
            for (int st = sz >> 1; st > 0; st >>= 1) {
                float ov = __shfl_xor(v, st);
                int oi = __shfl_xor(id, st);
                bool up = ((tid & sz) == 0);
                bool lower = ((tid & st) == 0);
                bool less = (v > ov) || (v == ov && id < oi);
                bool keep = (up == lower) ? less : !less;
                if (!keep) { v = ov; id = oi; }
            }
        if (tid < kk) { perm[tid] = id; svals[tid] = v; }
    }
    __syncthreads();
    for (int idx = tid; idx < n * 13; idx += UT) {
        int m = idx / 13, u0 = (idx - (idx / 13) * 13) * 4;
        float4 gv;
        gv.x = (u0 + 0 < kk) ? pA[m * ASTR + perm[u0 + 0]] : 0.f;
        gv.y = (u0 + 1 < kk) ? pA[m * ASTR + perm[u0 + 1]] : 0.f;
        gv.z = (u0 + 2 < kk) ? pA[m * ASTR + perm[u0 + 2]] : 0.f;
        gv.w = (u0 + 3 < kk) ? pA[m * ASTR + perm[u0 + 3]] : 0.f;
        *(float4*)&pt_[m * XS + u0] = gv;
    }
    float gx0=0, gx1=0, gx2=0, gx3=0; int gdst = -1;
    if (tid < kk * 13) {
        int t = tid / 13, q0 = (tid - t * 13) * 4;
        float sv = svals[t]; int p = perm[t];
        gx0 = px[p * XS + q0 + 0] * sv; gx1 = px[p * XS + q0 + 1] * sv;
        gx2 = px[p * XS + q0 + 2] * sv; gx3 = px[p * XS + q0 + 3] * sv;
        gdst = t * XS + q0;
    }
    __syncthreads();
    if (gdst >= 0) {
        px[gdst] = gx0; px[gdst + 1] = gx1; px[gdst + 2] = gx2; px[gdst + 3] = gx3;
    }
    int nst = (kk + 3) >> 2;
    for (int it = tid; it < kk * nst; it += UT) {
        int t = it / nst, u0 = (it - t * nst) * 4;
        int p = perm[t];
        float a0=0,a1=0,a2=0,a3=0, c0=0,c1=0,c2=0,c3=0;
        for (int m = 0; m < n; m += 2) {
            float4 g0 = *(const float4*)&pt_[m * XS + u0];
            float4 g1 = *(const float4*)&pt_[(m + 1) * XS + u0];
            float q0v = pA[p * ASTR + m], q1v = pA[p * ASTR + m + 1];
            a0 = fmaf(q0v, g0.x, a0); a1 = fmaf(q0v, g0.y, a1);
            a2 = fmaf(q0v, g0.z, a2); a3 = fmaf(q0v, g0.w, a3);
            c0 = fmaf(q1v, g1.x, c0); c1 = fmaf(q1v, g1.y, c1);
            c2 = fmaf(q1v, g1.z, c2); c3 = fmaf(q1v, g1.w, c3);
        }
        float4 gg = *(const float4*)&pt_[p * XS + u0];
        float v;
        v = (a0 + c0) + 2.f * gg.x; pF[t * ASTR + u0 + 0] = (u0 + 0 == t) ? 0.f : v;
        v = (a1 + c1) + 2.f * gg.y; pF[t * ASTR + u0 + 1] = (u0 + 1 == t) ? 0.f : v;
        v = (a2 + c2) + 2.f * gg.z; pF[t * ASTR + u0 + 2] = (u0 + 2 == t) ? 0.f : v;
        v = (a3 + c3) + 2.f * gg.w; pF[t * ASTR + u0 + 3] = (u0 + 3 == t) ? 0.f : v;
    }
    __syncthreads();
    gcn_u(kk, 50, 50, px, pt_, pF, pA, dis, dw, db, true);
}

// ---------------------------------------------------------------------------
// UNet kernel (round-5, proven): sparse CSR path for the two A0 gcns.
// ---------------------------------------------------------------------------
__global__ __launch_bounds__(UT)
void unet_kernel(const float* __restrict__ xin, const float* __restrict__ wsA,
                 const int* __restrict__ wsCsrO, const int* __restrict__ wsCsrC,
                 const float* __restrict__ dw0, const float* __restrict__ db0,
                 const float* __restrict__ dws, const float* __restrict__ dbs,
                 const float* __restrict__ pws,
                 const float* __restrict__ uws, const float* __restrict__ ubs,
                 const float* __restrict__ uwl, const float* __restrict__ ubl,
                 float* __restrict__ ws_xs, float* __restrict__ ws_As,
                 float* __restrict__ outp, int mean_mode)
{
    const int g = blockIdx.x, tid = threadIdx.x;
    __shared__ __align__(16) float Aa[64 * ASTR];
    __shared__ __align__(16) float Ab[64 * ASTR];
    __shared__ __align__(16) float x0c[64 * XS];
    __shared__ __align__(16) float x1c[64 * XS];
    __shared__ float scr[64];
    __shared__ float dis[64];
    __shared__ float dis0[64];
    __shared__ float svals[64];
    __shared__ int   permL[192];
    __shared__ int   csrOffL[65];
    __shared__ int   csrColL[512];

    float *pA = Aa, *pF = Ab, *px = x0c, *pt_ = x1c;
    float* xs_g = ws_xs + (size_t)g * 9984;   // 3 x 3328
    float* as_g = ws_As + (size_t)g * 6144;   // A1(3380) + A2(2730)
    const float* wsAg = wsA + (size_t)g * 4160;
    const int nsz[4] = {64, 52, 42, 34};

    {   // initial loads
        const float* xg = xin + (size_t)g * 2048;
        for (int idx = tid; idx < 512; idx += UT) {
            int i = idx >> 3, o0 = (idx & 7) * 4;
            *(float4*)&px[i * XS + o0] = *(const float4*)&xg[i * 32 + o0];
        }
        for (int idx = tid; idx < 4160; idx += UT) pA[idx] = wsAg[idx];
        if (tid < 65) csrOffL[tid] = wsCsrO[(size_t)g * 66 + tid];
        if (tid >= 128 && tid < 640) csrColL[tid - 128] = wsCsrC[(size_t)g * 512 + tid - 128];
    }
    __syncthreads();

    gcn_sparse(32, 50, px, pt_, csrOffL, csrColL, dis0, pF, dw0, db0, true);

    // ---- down path ----
    for (int lvl = 0; lvl < 3; lvl++) {
        int n = nsz[lvl], kk = nsz[lvl + 1];
        down_scores(n, pws + lvl * 50, px, scr);
        {   // skip saves
            float* xd = xs_g + lvl * 3328;
            for (int idx = tid; idx < 3328; idx += UT) xd[idx] = px[idx];
            if (lvl == 1) for (int idx = tid; idx < 3380; idx += UT) as_g[idx] = pA[idx];
            if (lvl == 2) for (int idx = tid; idx < 2730; idx += UT) as_g[3380 + idx] = pA[idx];
        }
        down_rest(n, kk, px, pt_, pA, pF, scr, dis, svals, permL + lvl * 64,
                  dws + lvl * 2500, dbs + lvl * 50);
        { float* t = pA; pA = pF; pF = t; }
    }

    // ---- up path ----
    for (int i2 = 0; i2 < 3; i2++) {
        int j = 2 - i2;
        int kc = nsz[j + 1];
        {   // residual into pt_; A into pF for dense levels only
            const float* resg = xs_g + j * 3328;
            for (int idx = tid; idx < 3328; idx += UT) pt_[idx] = resg[idx];
            if (j == 1) {
                for (int idx = tid; idx < 3380; idx += UT) pF[idx] = as_g[idx];
            } else if (j == 2) {
                for (int idx = tid; idx < 2730; idx += UT) pF[idx] = as_g[3380 + idx];
            }
        }
        __syncthreads();
        const int* perm = permL + j * 64;
        for (int it = tid; it < kc * 13; it += UT) {
            int t = it / 13, q0 = (it - t * 13) * 4;
            int p = perm[t];
            pt_[p*XS+q0+0] += px[t*XS+q0+0]; pt_[p*XS+q0+1] += px[t*XS+q0+1];
            pt_[p*XS+q0+2] += px[t*XS+q0+2]; pt_[p*XS+q0+3] += px[t*XS+q0+3];
        }
        __syncthreads();
        if (i2 < 2)
            gcn_u(nsz[j], 50, 50, pt_, px, pF, pA, dis, uws + i2 * 2500, ubs + i2 * 50, true);
        else
            gcn_sparse(50, 32, pt_, px, csrOffL, csrColL, dis0, pF, uwl, ubl, false);
        { float* t2 = px; px = pt_; pt_ = t2; }
        { float* t2 = pA; pA = pF; pF = t2; }
    }

    // epilogue
    if (mean_mode) {
        int r = tid >> 4, l = tid & 15;
        if (r < 32) {
            float s = 0.f;
            for (int i = l; i < 64; i += 16) s += fmaxf(px[i * XS + r], 0.f);
            s = wred16(s);
            if (l == 0) outp[(size_t)g * 32 + r] = s * (1.0f / 64.0f);
        }
    } else {
        float* og = outp + (size_t)g * 2048;
        for (int idx = tid; idx < 512; idx += UT) {
            int i = idx >> 3, o0 = (idx & 7) * 4;
            float4 vv = *(const float4*)&px[i * XS + o0];
            vv.x = fmaxf(vv.x, 0.f); vv.y = fmaxf(vv.y, 0.f);
            vv.z = fmaxf(vv.z, 0.f); vv.w = fmaxf(vv.w, 0.f);
            *(float4*)&og[i * 32 + o0] = vv;
        }
    }
}

// ---------------------------------------------------------------------------
// NNConv core, dst-grouped & atomic-free. Wave layout: o=lane&31, ic=lane>=32.
// One dst per wave-iteration (wave-uniform edge run from dst-CSR). Weights for
// this lane's (ic-chunk, o) column live in registers; x read as broadcast
// b128; one plain store per (d,o). cnt comes exactly from dOff diffs.
// ---------------------------------------------------------------------------
template<int FIN>
__device__ __forceinline__ void nnconv_core(
    const float* __restrict__ xl, const float* __restrict__ rwl,
    float* __restrict__ agg,
    const int* __restrict__ dOff, const int* __restrict__ sSrc,
    const float* __restrict__ sEa,
    const float* __restrict__ mw, const float* __restrict__ mb,
    const float* __restrict__ bias, float* __restrict__ xout_g)
{
    constexpr int CH = FIN / 2;
    const int tid = threadIdx.x;
    const int o = tid & 31, ic = (tid >> 5) & 1, wv = tid >> 6;
    float mwr[CH], mbr[CH];
    #pragma unroll
    for (int z = 0; z < CH; z++) {
        mwr[z] = mw[(ic * CH + z) * 32 + o];
        mbr[z] = mb[(ic * CH + z) * 32 + o];
    }
    for (int dd = 0; dd < 4; dd++) {
        int d = wv * 4 + dd;                  // wave-uniform
        int b = dOff[d], e = dOff[d + 1];
        float ac0 = 0.f, ac1 = 0.f, ac2 = 0.f, ac3 = 0.f;
        for (int p = b; p < e; p++) {
            int s = sSrc[p];                  // broadcast
            float av = sEa[p];
            #pragma unroll
            for (int z = 0; z < CH; z += 4) {
                float4 xv = *(const float4*)&xl[s * FIN + ic * CH + z];
                ac0 = fmaf(xv.x, fmaxf(fmaf(av, mwr[z + 0], mbr[z + 0]), 0.f), ac0);
                ac1 = fmaf(xv.y, fmaxf(fmaf(av, mwr[z + 1], mbr[z + 1]), 0.f), ac1);
                ac2 = fmaf(xv.z, fmaxf(fmaf(av, mwr[z + 2], mbr[z + 2]), 0.f), ac2);
                ac3 = fmaf(xv.w, fmaxf(fmaf(av, mwr[z + 3], mbr[z + 3]), 0.f), ac3);
            }
        }
        float acc = (ac0 + ac1) + (ac2 + ac3);
        acc += __shfl_down(acc, 32);          // fold ic=1 into ic=0
        if (ic == 0) agg[d * 32 + o] = acc;   // unique writer, no atomic
    }
    __syncthreads();
    {   // epilogue: 1024 items = (node, o-pair)
        int nn = tid >> 4, o0 = (tid & 15) * 2;
        float a0 = 0.f, a1 = 0.f, b0 = 0.f, b1 = 0.f;
        for (int i = 0; i < FIN; i += 2) {
            float xv0 = xl[nn * FIN + i], xv1 = xl[nn * FIN + i + 1];
            float2 w0 = *(const float2*)&rwl[i * 32 + o0];
            float2 w1 = *(const float2*)&rwl[(i + 1) * 32 + o0];
            a0 = fmaf(xv0, w0.x, a0); a1 = fmaf(xv0, w0.y, a1);
            b0 = fmaf(xv1, w1.x, b0); b1 = fmaf(xv1, w1.y, b1);
        }
        float cn  = (float)(dOff[nn + 1] - dOff[nn]);
        float inv = 1.0f / fmaxf(cn, 1.f);
        float2 sv = *(const float2*)&agg[nn * 32 + o0];
        xout_g[nn * 32 + o0]     = fmaxf(fmaf(sv.x, inv, (a0 + b0) + bias[o0]),     0.f);
        xout_g[nn * 32 + o0 + 1] = fmaxf(fmaf(sv.y, inv, (a1 + b1) + bias[o0 + 1]), 0.f);
    }
}

// ---------------------------------------------------------------------------
// NNConv1 (FIN=64): builds A image + dedup CSR + stable dst-sorted edge list
// (persisted to ws), then runs the atomic-free conv.
// ---------------------------------------------------------------------------
__global__ __launch_bounds__(UT)
void nnconv1_kernel(const float* __restrict__ x1, const float* __restrict__ x2,
                    const int* __restrict__ ei1, const int* __restrict__ ei2,
                    const float* __restrict__ ea1, const float* __restrict__ ea2,
                    const float* __restrict__ mw, const float* __restrict__ mb,
                    const float* __restrict__ rw, const float* __restrict__ bias,
                    float* __restrict__ wsA, int* __restrict__ wsEdg,
                    int* __restrict__ wsCsrO, int* __restrict__ wsCsrC,
                    float* __restrict__ xout)
{
    const int g = blockIdx.x, tid = threadIdx.x;
    __shared__ __align__(16) float xl[4096];
    __shared__ __align__(16) float rwl[2048];
    __shared__ __align__(16) float agg[2048];    // aliased as chunkCnt in build
    __shared__ __align__(16) float Al[4160];
    __shared__ int   srcl[512];
    __shared__ int   dstl[512];
    __shared__ float eal[512];
    __shared__ int   sSrc[512];
    __shared__ float sEaL[512];
    __shared__ int   sTot[64];
    __shared__ int   dOff[65];
    __shared__ int   rowc[64];
    __shared__ int   csrOffL[65];

    const float* xg; const int* eig; const float* eag;
    if (g < 128) {
        xg = x1 + (size_t)g * 4096; eig = ei1 + (size_t)g * 1024; eag = ea1 + (size_t)g * 512;
    } else {
        int h = g - 128;
        xg = x2 + (size_t)h * 4096; eig = ei2 + (size_t)h * 1024; eag = ea2 + (size_t)h * 512;
    }
    int* chunkCnt = (int*)agg;                   // 16 chunks x 64 dsts

    // step 1: loads + zeroing
    *(float4*)&xl[tid * 4] = *(const float4*)&xg[tid * 4];   // 1024 x float4
    if (tid < 512) { srcl[tid] = eig[tid]; dstl[tid] = eig[512 + tid]; eal[tid] = eag[tid]; }
    for (int i = tid; i < 4160; i += UT) Al[i] = 0.f;
    chunkCnt[tid] = 0;
    __syncthreads();
    // step 2: A scatter + per-chunk dst counts
    if (tid < 512) {
        Al[dstl[tid] * ASTR + srcl[tid]] = 1.f;
        atomicAdd(&chunkCnt[(tid >> 5) * 64 + dstl[tid]], 1);
    }
    __syncthreads();
    // step 3: diag zero; per-dst chunk-exclusive run
    if (tid < 64) {
        Al[tid * ASTR + tid] = 0.f;
        int run = 0;
        for (int c = 0; c < 16; c++) {
            int t = chunkCnt[c * 64 + tid];
            chunkCnt[c * 64 + tid] = run; run += t;
        }
        sTot[tid] = run;
    }
    __syncthreads();
    // step 4: dst prefix (wave 0); csr row counts; rwl; persist wsA
    if (tid < 64) {
        int v = sTot[tid]; int x = v;
        #pragma unroll
        for (int dl = 1; dl < 64; dl <<= 1) {
            int y = __shfl_up(x, dl);
            if (tid >= dl) x += y;
        }
        dOff[tid] = x - v;
        if (tid == 63) dOff[64] = x;
    }
    if (tid >= 64 && tid < 128) {
        int i = tid - 64; int c = 0;
        for (int j = 0; j < 64; j++) c += (Al[i * ASTR + j] != 0.f) ? 1 : 0;
        rowc[i] = c;
    }
    for (int i = tid; i < 2048; i += UT) rwl[i] = rw[i];
    for (int i = tid; i < 4160; i += UT) wsA[(size_t)g * 4160 + i] = Al[i];
    __syncthreads();
    // step 5: csr prefix (wave 0); stable dst-sorted scatter
    if (tid < 64) {
        int v = rowc[tid]; int x = v;
        #pragma unroll
        for (int dl = 1; dl < 64; dl <<= 1) {
            int y = __shfl_up(x, dl);
            if (tid >= dl) x += y;
        }
        csrOffL[tid] = x - v;
        if (tid == 63) csrOffL[64] = x;
    }
    if (tid < 512) {
        int dk = dstl[tid]; int c = tid >> 5; int lr = 0;
        for (int e2 = (c << 5); e2 < tid; e2++) lr += (dstl[e2] == dk) ? 1 : 0;
        int pos = dOff[dk] + chunkCnt[c * 64 + dk] + lr;
        sSrc[pos] = srcl[tid]; sEaL[pos] = eal[tid];
    }
    __syncthreads();
    // step 6: persist csr + dst-sorted edges + dOff
    if (tid < 64) {
        int p = csrOffL[tid];
        for (int j = 0; j < 64; j++)
            if (Al[tid * ASTR + j] != 0.f) wsCsrC[(size_t)g * 512 + (p++)] = j;
    }
    if (tid >= 64 && tid < 129) wsCsrO[(size_t)g * 66 + (tid - 64)] = csrOffL[tid - 64];
    if (tid >= 192 && tid < 257) wsEdg[(size_t)g * 1152 + (tid - 192)] = dOff[tid - 192];
    if (tid < 512) {
        wsEdg[(size_t)g * 1152 + 66 + tid] = sSrc[tid];
        ((float*)wsEdg)[(size_t)g * 1152 + 578 + tid] = sEaL[tid];
    }
    __syncthreads();

    nnconv_core<64>(xl, rwl, agg, dOff, sSrc, sEaL, mw, mb, bias,
                    xout + (size_t)g * 2048);
}

// ---------------------------------------------------------------------------
// NNConv2 (FIN=32): loads pre-built dst-CSR edges from ws.
// ---------------------------------------------------------------------------
__global__ __launch_bounds__(UT)
void nnconv2_kernel(const float* __restrict__ xin,
                    const int* __restrict__ wsEdg,
                    const float* __restrict__ mw, const float* __restrict__ mb,
                    const float* __restrict__ rw, const float* __restrict__ bias,
                    float* __restrict__ xout)
{
    const int g = blockIdx.x, tid = threadIdx.x;
    __shared__ __align__(16) float xl[2048];
    __shared__ __align__(16) float rwl[1024];
    __shared__ __align__(16) float agg[2048];
    __shared__ int   dOff[65];
    __shared__ int   sSrc[512];
    __shared__ float sEaL[512];

    const float* xg = xin + (size_t)g * 2048;
    if (tid < 512) *(float4*)&xl[tid * 4] = *(const float4*)&xg[tid * 4];
    if (tid < 1024) rwl[tid] = rw[tid];
    if (tid < 65) dOff[tid] = wsEdg[(size_t)g * 1152 + tid];
    if (tid >= 128 && tid < 640) {
        sSrc[tid - 128] = wsEdg[(size_t)g * 1152 + 66 + (tid - 128)];
        sEaL[tid - 128] = ((const float*)wsEdg)[(size_t)g * 1152 + 578 + (tid - 128)];
    }
    __syncthreads();

    nnconv_core<32>(xl, rwl, agg, dOff, sSrc, sEaL, mw, mb, bias,
                    xout + (size_t)g * 2048);
}

// ---------------------------------------------------------------------------
// Head: out[b,h] = relu([r1,jw1,r2,jw2] @ bb_w + bb_b)
// ---------------------------------------------------------------------------
__global__ __launch_bounds__(256)
void head_kernel(const float* __restrict__ r,
                 const float* __restrict__ jw1, const float* __restrict__ jw2,
                 const float* __restrict__ bw, const float* __restrict__ bb,
                 float* __restrict__ out)
{
    const int b = blockIdx.x, h = threadIdx.x;
    float acc = bb[h];
    const float* r1 = r + (size_t)b * 32;
    const float* r2 = r + (size_t)(128 + b) * 32;
    #pragma unroll
    for (int q = 0; q < 32; q++) acc += r1[q] * bw[q * 256 + h];
    #pragma unroll
    for (int q = 0; q < 16; q++) acc += jw1[b * 16 + q] * bw[(32 + q) * 256 + h];
    #pragma unroll
    for (int q = 0; q < 32; q++) acc += r2[q] * bw[(48 + q) * 256 + h];
    #pragma unroll
    for (int q = 0; q < 16; q++) acc += jw2[b * 16 + q] * bw[(80 + q) * 256 + h];
    out[(size_t)b * 256 + h] = fmaxf(acc, 0.f);
}

// ---------------------------------------------------------------------------
extern "C" void kernel_launch(void* const* d_in, const int* in_sizes, int n_in,
                              void* d_out, int out_size, void* d_ws, size_t ws_size,
                              hipStream_t stream)
{
    const float* x1  = (const float*)d_in[0];
    const int*   ei1 = (const int*)  d_in[1];
    const float* ea1 = (const float*)d_in[2];
    const float* jw1 = (const float*)d_in[3];
    const float* x2  = (const float*)d_in[4];
    const int*   ei2 = (const int*)  d_in[5];
    const float* ea2 = (const float*)d_in[6];
    const float* jw2 = (const float*)d_in[7];
    const float* m1w = (const float*)d_in[8];
    const float* m1b = (const float*)d_in[9];
    const float* r1w = (const float*)d_in[10];
    const float* c1b = (const float*)d_in[11];
    const float* m2w = (const float*)d_in[12];
    const float* m2b = (const float*)d_in[13];
    const float* r2w = (const float*)d_in[14];
    const float* c2b = (const float*)d_in[15];
    const float* u1p[9]; for (int i = 0; i < 9; i++) u1p[i] = (const float*)d_in[16 + i];
    const float* u2p[9]; for (int i = 0; i < 9; i++) u2p[i] = (const float*)d_in[25 + i];
    const float* bbw = (const float*)d_in[34];
    const float* bbb = (const float*)d_in[35];

    char* ws = (char*)d_ws;
    size_t off = 0;
    float* wsA  = (float*)(ws + off); off += 256ull * 4160 * 4;
    float* xc1  = (float*)(ws + off); off += 256ull * 2048 * 4;
    float* xu1  = (float*)(ws + off); off += 256ull * 2048 * 4;
    float* xc2  = (float*)(ws + off); off += 256ull * 2048 * 4;
    float* rr   = (float*)(ws + off); off += 256ull * 32 * 4;
    float* wxs  = (float*)(ws + off); off += 256ull * 9984 * 4;
    float* wAs  = (float*)(ws + off); off += 256ull * 6144 * 4;
    int*   wEdg = (int*)  (ws + off); off += 256ull * 1152 * 4;
    int*   wCsO = (int*)  (ws + off); off += 256ull * 66 * 4;
    int*   wCsC = (int*)  (ws + off); off += 256ull * 512 * 4;
    (void)ws_size; (void)in_sizes; (void)n_in; (void)out_size;

    nnconv1_kernel<<<256, UT, 0, stream>>>(x1, x2, ei1, ei2, ea1, ea2,
                                           m1w, m1b, r1w, c1b,
                                           wsA, wEdg, wCsO, wCsC, xc1);
    unet_kernel<<<256, UT, 0, stream>>>(xc1, wsA, wCsO, wCsC,
        u1p[0], u1p[1], u1p[2], u1p[3], u1p[4], u1p[5], u1p[6], u1p[7], u1p[8],
        wxs, wAs, xu1, 0);
    nnconv2_kernel<<<256, UT, 0, stream>>>(xu1, wEdg, m2w, m2b, r2w, c2b, xc2);
    unet_kernel<<<256, UT, 0, stream>>>(xc2, wsA, wCsO, wCsC,
        u2p[0], u2p[1], u2p[2], u2p[3], u2p[4], u2p[5], u2p[6], u2p[7], u2p[8],
        wxs, wAs, rr, 1);
    head_kernel<<<128, 256, 0, stream>>>(rr, jw1, jw2, bbw, bbb, (float*)d_out);
}